// Round 9
// baseline (827.213 us; speedup 1.0000x reference)
//
#include <hip/hip_runtime.h>

#define N_NODES 100000
#define N_EDGES 1600000
#define NB (N_EDGES / 64)  // 25000 edge blocks
#define PITCH 68  // fp32 LDS pitch (node/out kernels)
#define PITCHH 72 // f16 LDS pitch: 144B row = 9 quads == 1 mod 8
#define N_SCAN_BLOCKS ((N_NODES + 1023) / 1024)  // 98

typedef _Float16 half8 __attribute__((ext_vector_type(8)));
typedef float f32x4 __attribute__((ext_vector_type(4)));

__device__ __forceinline__ int wave_c0() {
  return __builtin_amdgcn_readfirstlane((int)((threadIdx.x >> 6) << 4));
}

// fp32 wave GEMM (node/out kernels)
template<bool RELU, bool BIAS>
__device__ __forceinline__ void wave_gemm16(const float* Alds, int lane, int c0,
                                            const float* __restrict__ W,
                                            const float* __restrict__ bias,
                                            float acc[16]) {
#pragma unroll
  for (int j = 0; j < 16; ++j) acc[j] = BIAS ? bias[c0 + j] : 0.0f;
  const float* arow = Alds + lane * PITCH;
#pragma unroll
  for (int k = 0; k < 64; k += 4) {
    const float4 a4 = *reinterpret_cast<const float4*>(arow + k);
    const float av[4] = {a4.x, a4.y, a4.z, a4.w};
#pragma unroll
    for (int kk = 0; kk < 4; ++kk) {
#pragma unroll
      for (int j = 0; j < 16; ++j)
        acc[j] = fmaf(av[kk], W[(k + kk) * 64 + c0 + j], acc[j]);
    }
  }
  if (RELU) {
#pragma unroll
    for (int j = 0; j < 16; ++j) acc[j] = fmaxf(acc[j], 0.0f);
  }
}

__device__ __forceinline__ void store4x4(float* dst, const float a[16]) {
#pragma unroll
  for (int q = 0; q < 4; ++q)
    *reinterpret_cast<float4*>(dst + q * 4) =
        make_float4(a[q * 4], a[q * 4 + 1], a[q * 4 + 2], a[q * 4 + 3]);
}

__device__ __forceinline__ void store16h(_Float16* dst, const float a[16]) {
  half8 h0, h1;
#pragma unroll
  for (int u = 0; u < 8; ++u) {
    h0[u] = (_Float16)a[u];
    h1[u] = (_Float16)a[8 + u];
  }
  *reinterpret_cast<half8*>(dst) = h0;
  *reinterpret_cast<half8*>(dst + 8) = h1;
}

// ---- weight prep: wt[m][j][k] = (f16)W_m[k][j]  (transposed, fp16) ----
__global__ __launch_bounds__(256) void wconv_kernel(const float* __restrict__ Wp2,
                                                    const float* __restrict__ Wa1,
                                                    const float* __restrict__ Wa2,
                                                    _Float16* __restrict__ wt) {
  int t = blockIdx.x * 256 + threadIdx.x;
  if (t >= 3 * 4096) return;
  int m = t >> 12, idx = t & 4095;
  int j = idx >> 6, k = idx & 63;
  const float* W = (m == 0) ? Wp2 : ((m == 1) ? Wa1 : Wa2);
  wt[m * 4096 + j * 64 + k] = (_Float16)W[k * 64 + j];
}

// ---- CSR build: histogram -> 3-kernel parallel scan -> scatter ----
__global__ __launch_bounds__(256) void hist_kernel(const int* __restrict__ ei,
                                                   int* __restrict__ counts) {
  int e = blockIdx.x * 256 + threadIdx.x;
  if (e < N_EDGES) atomicAdd(&counts[ei[N_EDGES + e]], 1);
}

// S1: per-block exclusive scan (1024 elems) + block totals
__global__ __launch_bounds__(1024) void scan1_kernel(const int* __restrict__ counts,
                                                     int* __restrict__ pexcl,
                                                     int* __restrict__ btot) {
  __shared__ int wsum[16];
  const int tid = threadIdx.x, lane = tid & 63, wid = tid >> 6;
  const int idx = blockIdx.x * 1024 + tid;
  const int val = (idx < N_NODES) ? counts[idx] : 0;
  int x = val;
#pragma unroll
  for (int o = 1; o < 64; o <<= 1) {
    int y = __shfl_up(x, o);
    if (lane >= o) x += y;
  }
  if (lane == 63) wsum[wid] = x;
  __syncthreads();
  if (wid == 0) {
    int s = (lane < 16) ? wsum[lane] : 0;
#pragma unroll
    for (int o = 1; o < 16; o <<= 1) {
      int y = __shfl_up(s, o);
      if (lane >= o) s += y;
    }
    if (lane < 16) wsum[lane] = s;
  }
  __syncthreads();
  const int woff = (wid > 0) ? wsum[wid - 1] : 0;
  const int incl = woff + x;
  if (idx < N_NODES) pexcl[idx] = incl - val;
  if (tid == 1023) btot[blockIdx.x] = incl;
}

// S2: single wave exclusive-scans the 98 block totals in place
__global__ __launch_bounds__(64) void scan2_kernel(int* __restrict__ btot) {
  const int lane = threadIdx.x;
  int carry = 0;
  for (int base = 0; base < N_SCAN_BLOCKS; base += 64) {
    const int ii = base + lane;
    const int v = (ii < N_SCAN_BLOCKS) ? btot[ii] : 0;
    int x = v;
#pragma unroll
    for (int o = 1; o < 64; o <<= 1) {
      int y = __shfl_up(x, o);
      if (lane >= o) x += y;
    }
    if (ii < N_SCAN_BLOCKS) btot[ii] = carry + x - v;  // exclusive
    carry += __shfl(x, 63);
  }
}

// S3: cursor = per-block exclusive + block offset
__global__ __launch_bounds__(256) void scan3_kernel(const int* __restrict__ pexcl,
                                                    const int* __restrict__ btot,
                                                    int* __restrict__ cursor) {
  const int idx = blockIdx.x * 256 + threadIdx.x;
  if (idx < N_NODES) cursor[idx] = pexcl[idx] + btot[idx >> 10];
}

__global__ __launch_bounds__(256) void scatter_kernel(const int* __restrict__ ei,
                                                      int* __restrict__ cursor,
                                                      int2* __restrict__ order2) {
  int e = blockIdx.x * 256 + threadIdx.x;
  if (e < N_EDGES) {
    int s = ei[e];
    int d = ei[N_EDGES + e];
    int p = atomicAdd(&cursor[d], 1);
    order2[p] = make_int2(s, d);
  }
}

// ---- Kernel A: h = relu(x@W_in+b_in); ad=h@W_dst; as=h@W_src; v=h@W_lin (fp16 out)
__global__ __launch_bounds__(256) void node_proj_kernel(
    const float* __restrict__ x, const float* __restrict__ W_in,
    const float* __restrict__ b_in, const float* __restrict__ W_lin,
    const float* __restrict__ W_src, const float* __restrict__ W_dst,
    _Float16* __restrict__ adh, _Float16* __restrict__ ash,
    _Float16* __restrict__ vh) {
  __shared__ __align__(16) float A[64 * PITCH];
  const int tid = threadIdx.x, lane = tid & 63, c0 = wave_c0();
  const int n0 = blockIdx.x * 64;
#pragma unroll
  for (int i = 0; i < 4; ++i) {
    int idx4 = tid + i * 256;
    int e = idx4 >> 4, k4 = (idx4 & 15) * 4;
    int n = n0 + e;
    float4 val = make_float4(0.f, 0.f, 0.f, 0.f);
    if (n < N_NODES) val = *reinterpret_cast<const float4*>(x + (size_t)n * 64 + k4);
    *reinterpret_cast<float4*>(&A[e * PITCH + k4]) = val;
  }
  __syncthreads();
  float h[16];
  wave_gemm16<true, true>(A, lane, c0, W_in, b_in, h);
  __syncthreads();
  store4x4(&A[lane * PITCH + c0], h);
  __syncthreads();
  float o1[16], o2[16], o3[16];
  wave_gemm16<false, false>(A, lane, c0, W_dst, nullptr, o1);
  wave_gemm16<false, false>(A, lane, c0, W_src, nullptr, o2);
  wave_gemm16<false, false>(A, lane, c0, W_lin, nullptr, o3);
  const int n = n0 + lane;
  if (n < N_NODES) {
    store16h(adh + (size_t)n * 64 + c0, o1);
    store16h(ash + (size_t)n * 64 + c0, o2);
    store16h(vh + (size_t)n * 64 + c0, o3);
  }
}

// MFMA helper: A-frag row = 16w + (lane&15), k = 8*(lane>>4)+e (+32).
// D: row = 16w + 4*(lane>>4)+r, col = 16t + (lane&15).
__device__ __forceinline__ void mfma3(const _Float16* aL, int w, int g, int a,
                                      const _Float16* __restrict__ Wt,
                                      const float* __restrict__ bias,
                                      f32x4 acc[4]) {
  const half8 A0 = *reinterpret_cast<const half8*>(aL + (16 * w + a) * PITCHH + 8 * g);
  const half8 A1 = *reinterpret_cast<const half8*>(aL + (16 * w + a) * PITCHH + 32 + 8 * g);
#pragma unroll
  for (int t = 0; t < 4; ++t) {
    const half8 B0 = *reinterpret_cast<const half8*>(Wt + (16 * t + a) * 64 + 8 * g);
    const half8 B1 = *reinterpret_cast<const half8*>(Wt + (16 * t + a) * 64 + 32 + 8 * g);
    const float bv = bias[16 * t + a];
    f32x4 c = {bv, bv, bv, bv};
    c = __builtin_amdgcn_mfma_f32_16x16x32_f16(A0, B0, c, 0, 0, 0);
    c = __builtin_amdgcn_mfma_f32_16x16x32_f16(A1, B1, c, 0, 0, 0);
    acc[t] = c;
  }
}

// ---- Kernel B: wave-private edge pipeline; 2 LDS buffers (18.4 KB -> 8 blk/CU)
// s_act lifecycle (wave-private 16 rows): hp -> delta (in place) -> a_in -> ha -> ex
// s_v holds v+delta (epilogue needs only the sum).
// pbuf layout per block: [slot(0=head,1=tail)][array(0=num,1=den)][64ch] fp32
// headd[b]: -1 = head segment complete; -2 = whole-block single segment; else d
// taild[b]: -1 = tail segment complete; else d
__global__ __launch_bounds__(256) void edge_kernel(
    const int2* __restrict__ order2, const float* __restrict__ pos,
    const float* __restrict__ Wp1, const float* __restrict__ bp1,
    const _Float16* __restrict__ wt, const float* __restrict__ bp2,
    const float* __restrict__ ba1, const float* __restrict__ ba2,
    const _Float16* __restrict__ adh, const _Float16* __restrict__ ash,
    const _Float16* __restrict__ vh, float* __restrict__ num,
    float* __restrict__ den, float* __restrict__ pbuf,
    int* __restrict__ headd, int* __restrict__ taild) {
  __shared__ _Float16 s_act[64 * PITCHH];  // hp -> delta -> a_in -> ha -> ex
  __shared__ _Float16 s_v[64 * PITCHH];    // v + delta
  const int tid = threadIdx.x, lane = tid & 63, w = tid >> 6;
  const int g = lane >> 4, a = lane & 15, c0 = w * 16;
  const int i = blockIdx.x * 64 + lane;  // sorted edge slot (E % 64 == 0)
  const int2 sd = order2[i];
  const int d = sd.y;                    // epilogue segment key
  // row-phase mapping: 4 threads per own-wave row (row er, quarter p)
  const int er = 16 * w + (lane >> 2);
  const int p = lane & 3;
  const int2 sd2 = order2[blockIdx.x * 64 + er];
  const int s2 = sd2.x, d2 = sd2.y;
  // prefetch node-row gathers NOW; consumed at a_in phase (overlap stage0+GEMM1)
  const _Float16* adr = adh + (size_t)d2 * 64 + 16 * p;
  const _Float16* asr = ash + (size_t)s2 * 64 + 16 * p;
  const _Float16* vr  = vh  + (size_t)s2 * 64 + 16 * p;
  const half8 ad0 = *reinterpret_cast<const half8*>(adr);
  const half8 ad1 = *reinterpret_cast<const half8*>(adr + 8);
  const half8 as0 = *reinterpret_cast<const half8*>(asr);
  const half8 as1 = *reinterpret_cast<const half8*>(asr + 8);
  const half8 v0  = *reinterpret_cast<const half8*>(vr);
  const half8 v1  = *reinterpret_cast<const half8*>(vr + 8);
  // boundary probes (partial-vs-complete decision)
  int dm1 = -1, dp1 = -1;
  if (lane == 0 && i > 0) dm1 = order2[i - 1].y;
  if (lane == 63 && i + 1 < N_EDGES) dp1 = order2[i + 1].y;
  dm1 = __shfl(dm1, 0);
  // stage0: hp(row er, ch 16p..16p+16) = relu(dpos@Wp1+bp1) -- wave-private rows
  {
    const float2 pd = reinterpret_cast<const float2*>(pos)[d2];
    const float2 ps = reinterpret_cast<const float2*>(pos)[s2];
    const float dx = pd.x - ps.x, dy = pd.y - ps.y;
    half8 h0, h1;
#pragma unroll
    for (int u = 0; u < 8; ++u) {
      const int j0 = 16 * p + u, j1 = 16 * p + 8 + u;
      h0[u] = (_Float16)fmaxf(fmaf(dx, Wp1[j0], fmaf(dy, Wp1[64 + j0], bp1[j0])), 0.f);
      h1[u] = (_Float16)fmaxf(fmaf(dx, Wp1[j1], fmaf(dy, Wp1[64 + j1], bp1[j1])), 0.f);
    }
    *reinterpret_cast<half8*>(&s_act[er * PITCHH + 16 * p]) = h0;
    *reinterpret_cast<half8*>(&s_act[er * PITCHH + 16 * p + 8]) = h1;
  }
  f32x4 acc[4];
  // GEMM1: delta = relu(hp@Wp2+bp2) -> write IN PLACE over hp (own 16 rows;
  // safe: lockstep wave has completed all A-frag ds_reads before these stores)
  mfma3(s_act, w, g, a, wt, bp2, acc);
#pragma unroll
  for (int t = 0; t < 4; ++t)
#pragma unroll
    for (int r = 0; r < 4; ++r)
      s_act[(16 * w + 4 * g + r) * PITCHH + 16 * t + a] =
          (_Float16)fmaxf(acc[t][r], 0.f);
  // a_in = ad[d]-as[s]+delta -> s_act (over delta); v+delta -> s_v  (own rows)
  {
    const half8 dl0 = *reinterpret_cast<const half8*>(&s_act[er * PITCHH + 16 * p]);
    const half8 dl1 = *reinterpret_cast<const half8*>(&s_act[er * PITCHH + 16 * p + 8]);
    *reinterpret_cast<half8*>(&s_act[er * PITCHH + 16 * p]) = ad0 - as0 + dl0;
    *reinterpret_cast<half8*>(&s_act[er * PITCHH + 16 * p + 8]) = ad1 - as1 + dl1;
    *reinterpret_cast<half8*>(&s_v[er * PITCHH + 16 * p]) = v0 + dl0;
    *reinterpret_cast<half8*>(&s_v[er * PITCHH + 16 * p + 8]) = v1 + dl1;
  }
  // GEMM2: ha = relu(a_in@Wa1+ba1) -> s_act (own rows)
  mfma3(s_act, w, g, a, wt + 4096, ba1, acc);
#pragma unroll
  for (int t = 0; t < 4; ++t)
#pragma unroll
    for (int r = 0; r < 4; ++r)
      s_act[(16 * w + 4 * g + r) * PITCHH + 16 * t + a] =
          (_Float16)fmaxf(acc[t][r], 0.f);
  // GEMM3: aat = relu(ha@Wa2+ba2); ex = exp(aat) -> s_act (own rows, over ha)
  mfma3(s_act, w, g, a, wt + 2 * 4096, ba2, acc);
#pragma unroll
  for (int t = 0; t < 4; ++t)
#pragma unroll
    for (int r = 0; r < 4; ++r)
      s_act[(16 * w + 4 * g + r) * PITCHH + 16 * t + a] =
          (_Float16)__expf(fmaxf(acc[t][r], 0.f));
  __syncthreads();  // ONLY barrier: cross-wave rows of s_act(ex)/s_v
  // epilogue (lane=edge, channels c0..c0+15)
  const half8 e0 = *reinterpret_cast<const half8*>(&s_act[lane * PITCHH + c0]);
  const half8 e1 = *reinterpret_cast<const half8*>(&s_act[lane * PITCHH + c0 + 8]);
  const half8 vd0 = *reinterpret_cast<const half8*>(&s_v[lane * PITCHH + c0]);
  const half8 vd1 = *reinterpret_cast<const half8*>(&s_v[lane * PITCHH + c0 + 8]);
  float vals[32];  // [0..15]=ex*(v+delta), [16..31]=ex
#pragma unroll
  for (int j = 0; j < 16; ++j) {
    const float ex = (float)((j < 8) ? e0[j] : e1[j - 8]);
    const float vd = (float)((j < 8) ? vd0[j] : vd1[j - 8]);
    vals[j] = ex * vd;
    vals[16 + j] = ex;
  }
  // wave-level segmented inclusive scan over contiguous equal-d runs
  const int dprev = __shfl_up(d, 1);
  const int dnext = __shfl_down(d, 1);
  const bool head = (lane == 0) || (d != dprev);
  const bool tail = (lane == 63) || (d != dnext);
  const unsigned long long hb = __ballot(head);
  const unsigned long long maskle =
      (lane == 63) ? ~0ull : ((1ull << (lane + 1)) - 1ull);
  const int myhead = 63 - __clzll(hb & maskle);
#pragma unroll
  for (int o = 1; o < 64; o <<= 1) {
    const bool c = (lane - o) >= myhead;
#pragma unroll
    for (int t = 0; t < 32; ++t) {
      float y = __shfl_up(vals[t], o);
      if (c) vals[t] += y;
    }
  }
  if (tail) {
    const bool ts = (myhead > 0) || (dm1 != d);  // segment starts in this block
    const bool te = (lane < 63) || (dp1 != d);   // segment ends in this block
    if (ts && te) {
      // complete segment: exclusive writer of this (d, chunk) -> plain stores
      float* np = num + (size_t)d * 64 + c0;
      float* dp_ = den + (size_t)d * 64 + c0;
#pragma unroll
      for (int q = 0; q < 4; ++q)
        *reinterpret_cast<float4*>(np + 4 * q) =
            make_float4(vals[4 * q], vals[4 * q + 1], vals[4 * q + 2], vals[4 * q + 3]);
#pragma unroll
      for (int q = 0; q < 4; ++q)
        *reinterpret_cast<float4*>(dp_ + 4 * q) =
            make_float4(vals[16 + 4 * q], vals[17 + 4 * q], vals[18 + 4 * q],
                        vals[19 + 4 * q]);
    } else {
      // partial segment: coalesced dump to pbuf; resolved by finish_kernel
      const int slot = (!ts && te) ? 0 : 1;  // head -> 0; tail/whole -> 1
      float* pb = pbuf + (size_t)blockIdx.x * 256 + slot * 128 + c0;
#pragma unroll
      for (int q = 0; q < 4; ++q)
        *reinterpret_cast<float4*>(pb + 4 * q) =
            make_float4(vals[4 * q], vals[4 * q + 1], vals[4 * q + 2], vals[4 * q + 3]);
#pragma unroll
      for (int q = 0; q < 4; ++q)
        *reinterpret_cast<float4*>(pb + 64 + 4 * q) =
            make_float4(vals[16 + 4 * q], vals[17 + 4 * q], vals[18 + 4 * q],
                        vals[19 + 4 * q]);
    }
    // markers (wave 0 only; segment structure identical across waves)
    if (w == 0) {
      if (myhead == 0) headd[blockIdx.x] = ts ? -1 : (te ? d : -2);
      if (lane == 63) taild[blockIdx.x] = te ? -1 : d;
    }
  }
}

// ---- finish: resolve boundary partials. Thread block b handles boundary
// between edge-blocks b-1 and b; owns tail[b-1] and head[b]. ----
__global__ __launch_bounds__(128) void finish_kernel(
    const float* __restrict__ pbuf, const int* __restrict__ headd,
    const int* __restrict__ taild, float* __restrict__ num,
    float* __restrict__ den) {
  const int b = blockIdx.x + 1;  // 1..NB-1
  const int t = taild[b - 1];
  if (t < 0) return;  // tail segment of b-1 complete; h>=0 implies t==h, so no drop
  const int ch = threadIdx.x & 63, arr = threadIdx.x >> 6;
  const int h = headd[b];
  const float tv = pbuf[(size_t)(b - 1) * 256 + 128 + arr * 64 + ch];
  float* dst = (arr ? den : num) + (size_t)t * 64 + ch;
  if (h == t) {
    const float hv = pbuf[(size_t)b * 256 + arr * 64 + ch];
    if (headd[b - 1] != -2) {
      *dst = tv + hv;  // chain is exactly {b-1, b}: exclusive owner
    } else {
      atomicAdd(dst, tv + hv);  // chain extends left (degree > 64; ~never)
    }
  } else {
    // h == -2: block b is whole-block same-d -> chain continues right
    atomicAdd(dst, tv);
  }
}

// ---- Kernel C: out = relu((num/(den+1e-16)) @ W_out + b_out) ----
__global__ __launch_bounds__(256) void out_kernel(
    const float* __restrict__ num, const float* __restrict__ den,
    const float* __restrict__ W_out, const float* __restrict__ b_out,
    float* __restrict__ out) {
  __shared__ __align__(16) float A[64 * PITCH];
  const int tid = threadIdx.x, lane = tid & 63, c0 = wave_c0();
  const int n0 = blockIdx.x * 64;
#pragma unroll
  for (int i = 0; i < 4; ++i) {
    int idx4 = tid + i * 256;
    int e = idx4 >> 4, k4 = (idx4 & 15) * 4;
    int n = n0 + e;
    float4 val = make_float4(0.f, 0.f, 0.f, 0.f);
    if (n < N_NODES) {
      float4 nu = *reinterpret_cast<const float4*>(num + (size_t)n * 64 + k4);
      float4 de = *reinterpret_cast<const float4*>(den + (size_t)n * 64 + k4);
      val.x = nu.x / (de.x + 1e-16f);
      val.y = nu.y / (de.y + 1e-16f);
      val.z = nu.z / (de.z + 1e-16f);
      val.w = nu.w / (de.w + 1e-16f);
    }
    *reinterpret_cast<float4*>(&A[e * PITCH + k4]) = val;
  }
  __syncthreads();
  float o[16];
  wave_gemm16<true, true>(A, lane, c0, W_out, b_out, o);
  const int n = n0 + lane;
  if (n < N_NODES) store4x4(out + (size_t)n * 64 + c0, o);
}

extern "C" void kernel_launch(void* const* d_in, const int* in_sizes, int n_in,
                              void* d_out, int out_size, void* d_ws,
                              size_t ws_size, hipStream_t stream) {
  const float* x     = (const float*)d_in[0];
  const float* pos   = (const float*)d_in[1];
  const int*   ei    = (const int*)d_in[2];
  const float* W_in  = (const float*)d_in[3];
  const float* b_in  = (const float*)d_in[4];
  const float* W_lin = (const float*)d_in[5];
  const float* W_src = (const float*)d_in[6];
  const float* W_dst = (const float*)d_in[7];
  const float* Wp1   = (const float*)d_in[8];
  const float* bp1   = (const float*)d_in[9];
  const float* Wp2   = (const float*)d_in[10];
  const float* bp2   = (const float*)d_in[11];
  const float* Wa1   = (const float*)d_in[12];
  const float* ba1   = (const float*)d_in[13];
  const float* Wa2   = (const float*)d_in[14];
  const float* ba2   = (const float*)d_in[15];
  const float* W_out = (const float*)d_in[16];
  const float* b_out = (const float*)d_in[17];
  float* out = (float*)d_out;

  const size_t NC = (size_t)N_NODES * 64;
  _Float16* adh = (_Float16*)d_ws;               // NC halfs
  _Float16* ash = adh + NC;                      // NC halfs
  _Float16* vh  = ash + NC;                      // NC halfs
  float* num = (float*)(vh + NC);                // NC floats
  float* den = num + NC;                         // NC floats
  int* counts = (int*)(den + NC);                // N_NODES ints
  int* cursor = counts + N_NODES;                // N_NODES ints
  int* pexcl  = cursor + N_NODES;                // N_NODES ints
  int* btot   = pexcl + N_NODES;                 // 128 ints
  int2* order2 = (int2*)(btot + 128);            // N_EDGES int2 (8B aligned)
  float* pbuf  = (float*)(order2 + N_EDGES);     // NB*256 floats (partials)
  int* headd   = (int*)(pbuf + (size_t)NB * 256);// NB ints
  int* taild   = headd + NB;                     // NB ints
  _Float16* wt = (_Float16*)(taild + NB);        // 3*4096 f16 (16B aligned)

  hipMemsetAsync(num, 0, 2 * NC * sizeof(float), stream);    // num+den
  hipMemsetAsync(counts, 0, N_NODES * sizeof(int), stream);  // histogram

  wconv_kernel<<<48, 256, 0, stream>>>(Wp2, Wa1, Wa2, wt);
  hist_kernel<<<(N_EDGES + 255) / 256, 256, 0, stream>>>(ei, counts);
  scan1_kernel<<<N_SCAN_BLOCKS, 1024, 0, stream>>>(counts, pexcl, btot);
  scan2_kernel<<<1, 64, 0, stream>>>(btot);
  scan3_kernel<<<(N_NODES + 255) / 256, 256, 0, stream>>>(pexcl, btot, cursor);
  scatter_kernel<<<(N_EDGES + 255) / 256, 256, 0, stream>>>(ei, cursor, order2);

  node_proj_kernel<<<(N_NODES + 63) / 64, 256, 0, stream>>>(
      x, W_in, b_in, W_lin, W_src, W_dst, adh, ash, vh);
  edge_kernel<<<NB, 256, 0, stream>>>(
      order2, pos, Wp1, bp1, wt, bp2, ba1, ba2, adh, ash, vh, num, den,
      pbuf, headd, taild);
  finish_kernel<<<NB - 1, 128, 0, stream>>>(pbuf, headd, taild, num, den);
  out_kernel<<<(N_NODES + 63) / 64, 256, 0, stream>>>(num, den, W_out, b_out, out);
}

// Round 10
// 788.337 us; speedup vs baseline: 1.0493x; 1.0493x over previous
//
#include <hip/hip_runtime.h>

#define N_NODES 100000
#define N_EDGES 1600000
#define NB (N_EDGES / 64)  // 25000 edge blocks
#define PITCH 68  // fp32 LDS pitch (node/out kernels)
#define PITCHH 72 // f16 LDS pitch: 144B row = 9 quads == 1 mod 8
#define N_SCAN_BLOCKS ((N_NODES + 1023) / 1024)  // 98

typedef _Float16 half8 __attribute__((ext_vector_type(8)));
typedef float f32x4 __attribute__((ext_vector_type(4)));

__device__ __forceinline__ int wave_c0() {
  return __builtin_amdgcn_readfirstlane((int)((threadIdx.x >> 6) << 4));
}

// fp32 wave GEMM (node/out kernels)
template<bool RELU, bool BIAS>
__device__ __forceinline__ void wave_gemm16(const float* Alds, int lane, int c0,
                                            const float* __restrict__ W,
                                            const float* __restrict__ bias,
                                            float acc[16]) {
#pragma unroll
  for (int j = 0; j < 16; ++j) acc[j] = BIAS ? bias[c0 + j] : 0.0f;
  const float* arow = Alds + lane * PITCH;
#pragma unroll
  for (int k = 0; k < 64; k += 4) {
    const float4 a4 = *reinterpret_cast<const float4*>(arow + k);
    const float av[4] = {a4.x, a4.y, a4.z, a4.w};
#pragma unroll
    for (int kk = 0; kk < 4; ++kk) {
#pragma unroll
      for (int j = 0; j < 16; ++j)
        acc[j] = fmaf(av[kk], W[(k + kk) * 64 + c0 + j], acc[j]);
    }
  }
  if (RELU) {
#pragma unroll
    for (int j = 0; j < 16; ++j) acc[j] = fmaxf(acc[j], 0.0f);
  }
}

__device__ __forceinline__ void store4x4(float* dst, const float a[16]) {
#pragma unroll
  for (int q = 0; q < 4; ++q)
    *reinterpret_cast<float4*>(dst + q * 4) =
        make_float4(a[q * 4], a[q * 4 + 1], a[q * 4 + 2], a[q * 4 + 3]);
}

__device__ __forceinline__ void store16h(_Float16* dst, const float a[16]) {
  half8 h0, h1;
#pragma unroll
  for (int u = 0; u < 8; ++u) {
    h0[u] = (_Float16)a[u];
    h1[u] = (_Float16)a[8 + u];
  }
  *reinterpret_cast<half8*>(dst) = h0;
  *reinterpret_cast<half8*>(dst + 8) = h1;
}

// ---- weight prep: wt[m][j][k] = (f16)W_m[k][j]  (transposed, fp16) ----
__global__ __launch_bounds__(256) void wconv_kernel(const float* __restrict__ Wp2,
                                                    const float* __restrict__ Wa1,
                                                    const float* __restrict__ Wa2,
                                                    _Float16* __restrict__ wt) {
  int t = blockIdx.x * 256 + threadIdx.x;
  if (t >= 3 * 4096) return;
  int m = t >> 12, idx = t & 4095;
  int j = idx >> 6, k = idx & 63;
  const float* W = (m == 0) ? Wp2 : ((m == 1) ? Wa1 : Wa2);
  wt[m * 4096 + j * 64 + k] = (_Float16)W[k * 64 + j];
}

// ---- CSR build: histogram -> 3-kernel parallel scan -> scatter ----
__global__ __launch_bounds__(256) void hist_kernel(const int* __restrict__ ei,
                                                   int* __restrict__ counts) {
  int e = blockIdx.x * 256 + threadIdx.x;
  if (e < N_EDGES) atomicAdd(&counts[ei[N_EDGES + e]], 1);
}

// S1: per-block exclusive scan (1024 elems) + block totals
__global__ __launch_bounds__(1024) void scan1_kernel(const int* __restrict__ counts,
                                                     int* __restrict__ pexcl,
                                                     int* __restrict__ btot) {
  __shared__ int wsum[16];
  const int tid = threadIdx.x, lane = tid & 63, wid = tid >> 6;
  const int idx = blockIdx.x * 1024 + tid;
  const int val = (idx < N_NODES) ? counts[idx] : 0;
  int x = val;
#pragma unroll
  for (int o = 1; o < 64; o <<= 1) {
    int y = __shfl_up(x, o);
    if (lane >= o) x += y;
  }
  if (lane == 63) wsum[wid] = x;
  __syncthreads();
  if (wid == 0) {
    int s = (lane < 16) ? wsum[lane] : 0;
#pragma unroll
    for (int o = 1; o < 16; o <<= 1) {
      int y = __shfl_up(s, o);
      if (lane >= o) s += y;
    }
    if (lane < 16) wsum[lane] = s;
  }
  __syncthreads();
  const int woff = (wid > 0) ? wsum[wid - 1] : 0;
  const int incl = woff + x;
  if (idx < N_NODES) pexcl[idx] = incl - val;
  if (tid == 1023) btot[blockIdx.x] = incl;
}

// S2: single wave exclusive-scans the 98 block totals in place
__global__ __launch_bounds__(64) void scan2_kernel(int* __restrict__ btot) {
  const int lane = threadIdx.x;
  int carry = 0;
  for (int base = 0; base < N_SCAN_BLOCKS; base += 64) {
    const int ii = base + lane;
    const int v = (ii < N_SCAN_BLOCKS) ? btot[ii] : 0;
    int x = v;
#pragma unroll
    for (int o = 1; o < 64; o <<= 1) {
      int y = __shfl_up(x, o);
      if (lane >= o) x += y;
    }
    if (ii < N_SCAN_BLOCKS) btot[ii] = carry + x - v;  // exclusive
    carry += __shfl(x, 63);
  }
}

// S3: cursor = per-block exclusive + block offset
__global__ __launch_bounds__(256) void scan3_kernel(const int* __restrict__ pexcl,
                                                    const int* __restrict__ btot,
                                                    int* __restrict__ cursor) {
  const int idx = blockIdx.x * 256 + threadIdx.x;
  if (idx < N_NODES) cursor[idx] = pexcl[idx] + btot[idx >> 10];
}

__global__ __launch_bounds__(256) void scatter_kernel(const int* __restrict__ ei,
                                                      int* __restrict__ cursor,
                                                      int2* __restrict__ order2) {
  int e = blockIdx.x * 256 + threadIdx.x;
  if (e < N_EDGES) {
    int s = ei[e];
    int d = ei[N_EDGES + e];
    int p = atomicAdd(&cursor[d], 1);
    order2[p] = make_int2(s, d);
  }
}

// ---- Kernel A: h = relu(x@W_in+b_in); ad=h@W_dst; as=h@W_src; v=h@W_lin (fp16 out)
__global__ __launch_bounds__(256) void node_proj_kernel(
    const float* __restrict__ x, const float* __restrict__ W_in,
    const float* __restrict__ b_in, const float* __restrict__ W_lin,
    const float* __restrict__ W_src, const float* __restrict__ W_dst,
    _Float16* __restrict__ adh, _Float16* __restrict__ ash,
    _Float16* __restrict__ vh) {
  __shared__ __align__(16) float A[64 * PITCH];
  const int tid = threadIdx.x, lane = tid & 63, c0 = wave_c0();
  const int n0 = blockIdx.x * 64;
#pragma unroll
  for (int i = 0; i < 4; ++i) {
    int idx4 = tid + i * 256;
    int e = idx4 >> 4, k4 = (idx4 & 15) * 4;
    int n = n0 + e;
    float4 val = make_float4(0.f, 0.f, 0.f, 0.f);
    if (n < N_NODES) val = *reinterpret_cast<const float4*>(x + (size_t)n * 64 + k4);
    *reinterpret_cast<float4*>(&A[e * PITCH + k4]) = val;
  }
  __syncthreads();
  float h[16];
  wave_gemm16<true, true>(A, lane, c0, W_in, b_in, h);
  __syncthreads();
  store4x4(&A[lane * PITCH + c0], h);
  __syncthreads();
  float o1[16], o2[16], o3[16];
  wave_gemm16<false, false>(A, lane, c0, W_dst, nullptr, o1);
  wave_gemm16<false, false>(A, lane, c0, W_src, nullptr, o2);
  wave_gemm16<false, false>(A, lane, c0, W_lin, nullptr, o3);
  const int n = n0 + lane;
  if (n < N_NODES) {
    store16h(adh + (size_t)n * 64 + c0, o1);
    store16h(ash + (size_t)n * 64 + c0, o2);
    store16h(vh + (size_t)n * 64 + c0, o3);
  }
}

// MFMA helper: A-frag row = 16w + (lane&15), k = 8*(lane>>4)+e (+32).
// D: row = 16w + 4*(lane>>4)+r, col = 16t + (lane&15).
__device__ __forceinline__ void mfma3(const _Float16* aL, int w, int g, int a,
                                      const _Float16* __restrict__ Wt,
                                      const float* __restrict__ bias,
                                      f32x4 acc[4]) {
  const half8 A0 = *reinterpret_cast<const half8*>(aL + (16 * w + a) * PITCHH + 8 * g);
  const half8 A1 = *reinterpret_cast<const half8*>(aL + (16 * w + a) * PITCHH + 32 + 8 * g);
#pragma unroll
  for (int t = 0; t < 4; ++t) {
    const half8 B0 = *reinterpret_cast<const half8*>(Wt + (16 * t + a) * 64 + 8 * g);
    const half8 B1 = *reinterpret_cast<const half8*>(Wt + (16 * t + a) * 64 + 32 + 8 * g);
    const float bv = bias[16 * t + a];
    f32x4 c = {bv, bv, bv, bv};
    c = __builtin_amdgcn_mfma_f32_16x16x32_f16(A0, B0, c, 0, 0, 0);
    c = __builtin_amdgcn_mfma_f32_16x16x32_f16(A1, B1, c, 0, 0, 0);
    acc[t] = c;
  }
}

// ---- Kernel B: wave-private edge pipeline; epilogue = MFMA segment-sum ----
// s_act: [edge][ch] hp -> delta -> a_in -> ha -> ex ; then transposed ext[ch][edge]
// s_v:   [edge][ch] v+delta ;                    then transposed exvdt[ch][edge]
// s_p:   P[seg][edge] in {0,1} fp16 (segment selection matrix)
// pbuf per block: [slot(0=head,1=tail)][array(0=num,1=den)][64ch] fp32
// headd[b]: -1 head seg complete; -2 whole-block single segment; else d
// taild[b]: -1 tail seg complete; else d
__global__ __launch_bounds__(256) void edge_kernel(
    const int2* __restrict__ order2, const float* __restrict__ pos,
    const float* __restrict__ Wp1, const float* __restrict__ bp1,
    const _Float16* __restrict__ wt, const float* __restrict__ bp2,
    const float* __restrict__ ba1, const float* __restrict__ ba2,
    const _Float16* __restrict__ adh, const _Float16* __restrict__ ash,
    const _Float16* __restrict__ vh, float* __restrict__ num,
    float* __restrict__ den, float* __restrict__ pbuf,
    int* __restrict__ headd, int* __restrict__ taild) {
  __shared__ __align__(16) _Float16 s_act[64 * PITCHH];
  __shared__ __align__(16) _Float16 s_v[64 * PITCHH];
  __shared__ __align__(16) _Float16 s_p[64 * PITCHH];
  __shared__ int s_segd[64];
  const int tid = threadIdx.x, lane = tid & 63, w = tid >> 6;
  const int g = lane >> 4, a = lane & 15, c0 = w * 16;
  const int i = blockIdx.x * 64 + lane;  // sorted edge slot (E % 64 == 0)
  // clear P + segd (read only after barriers below)
#pragma unroll
  for (int q = tid; q < 576; q += 256)
    *reinterpret_cast<int4*>(&s_p[q * 8]) = make_int4(0, 0, 0, 0);
  if (tid < 64) s_segd[tid] = -1;
  const int2 sd = order2[i];
  const int d = sd.y;  // segment key
  // row-phase mapping: 4 threads per own-wave row (row er, quarter p)
  const int er = 16 * w + (lane >> 2);
  const int p = lane & 3;
  const int2 sd2 = order2[blockIdx.x * 64 + er];
  const int s2 = sd2.x, d2 = sd2.y;
  // prefetch node-row gathers NOW; consumed at a_in phase
  const _Float16* adr = adh + (size_t)d2 * 64 + 16 * p;
  const _Float16* asr = ash + (size_t)s2 * 64 + 16 * p;
  const _Float16* vr  = vh  + (size_t)s2 * 64 + 16 * p;
  const half8 ad0 = *reinterpret_cast<const half8*>(adr);
  const half8 ad1 = *reinterpret_cast<const half8*>(adr + 8);
  const half8 as0 = *reinterpret_cast<const half8*>(asr);
  const half8 as1 = *reinterpret_cast<const half8*>(asr + 8);
  const half8 v0  = *reinterpret_cast<const half8*>(vr);
  const half8 v1  = *reinterpret_cast<const half8*>(vr + 8);
  // boundary probes
  int dm1 = -1, dp1 = -1;
  if (lane == 0 && i > 0) dm1 = order2[i - 1].y;
  if (lane == 63 && i + 1 < N_EDGES) dp1 = order2[i + 1].y;
  dm1 = __shfl(dm1, 0);
  dp1 = __shfl(dp1, 63);
  // segment structure (identical across waves)
  const int dprev = __shfl_up(d, 1);
  const bool head = (lane == 0) || (d != dprev);
  const unsigned long long hb = __ballot(head);
  const unsigned long long maskle =
      (lane == 63) ? ~0ull : ((1ull << (lane + 1)) - 1ull);
  const int sid = __popcll(hb & maskle) - 1;  // this edge's segment id
  const int nseg = __popcll(hb);
  const int d0 = __shfl(d, 0), dl = __shfl(d, 63);
  // stage0: hp(row er, ch 16p..16p+16) = relu(dpos@Wp1+bp1) -- wave-private rows
  {
    const float2 pd = reinterpret_cast<const float2*>(pos)[d2];
    const float2 ps = reinterpret_cast<const float2*>(pos)[s2];
    const float dx = pd.x - ps.x, dy = pd.y - ps.y;
    half8 h0, h1;
#pragma unroll
    for (int u = 0; u < 8; ++u) {
      const int j0 = 16 * p + u, j1 = 16 * p + 8 + u;
      h0[u] = (_Float16)fmaxf(fmaf(dx, Wp1[j0], fmaf(dy, Wp1[64 + j0], bp1[j0])), 0.f);
      h1[u] = (_Float16)fmaxf(fmaf(dx, Wp1[j1], fmaf(dy, Wp1[64 + j1], bp1[j1])), 0.f);
    }
    *reinterpret_cast<half8*>(&s_act[er * PITCHH + 16 * p]) = h0;
    *reinterpret_cast<half8*>(&s_act[er * PITCHH + 16 * p + 8]) = h1;
  }
  f32x4 acc[4];
  // GEMM1: delta = relu(hp@Wp2+bp2) -> in place over hp (own 16 rows)
  mfma3(s_act, w, g, a, wt, bp2, acc);
#pragma unroll
  for (int t = 0; t < 4; ++t)
#pragma unroll
    for (int r = 0; r < 4; ++r)
      s_act[(16 * w + 4 * g + r) * PITCHH + 16 * t + a] =
          (_Float16)fmaxf(acc[t][r], 0.f);
  // a_in = ad[d]-as[s]+delta -> s_act (over delta); v+delta -> s_v  (own rows)
  {
    const half8 dl0 = *reinterpret_cast<const half8*>(&s_act[er * PITCHH + 16 * p]);
    const half8 dl1 = *reinterpret_cast<const half8*>(&s_act[er * PITCHH + 16 * p + 8]);
    *reinterpret_cast<half8*>(&s_act[er * PITCHH + 16 * p]) = ad0 - as0 + dl0;
    *reinterpret_cast<half8*>(&s_act[er * PITCHH + 16 * p + 8]) = ad1 - as1 + dl1;
    *reinterpret_cast<half8*>(&s_v[er * PITCHH + 16 * p]) = v0 + dl0;
    *reinterpret_cast<half8*>(&s_v[er * PITCHH + 16 * p + 8]) = v1 + dl1;
  }
  // GEMM2: ha = relu(a_in@Wa1+ba1) -> s_act (own rows)
  mfma3(s_act, w, g, a, wt + 4096, ba1, acc);
#pragma unroll
  for (int t = 0; t < 4; ++t)
#pragma unroll
    for (int r = 0; r < 4; ++r)
      s_act[(16 * w + 4 * g + r) * PITCHH + 16 * t + a] =
          (_Float16)fmaxf(acc[t][r], 0.f);
  // GEMM3: aat = relu(ha@Wa2+ba2); ex = exp(aat) -> s_act (own rows, over ha)
  mfma3(s_act, w, g, a, wt + 2 * 4096, ba2, acc);
#pragma unroll
  for (int t = 0; t < 4; ++t)
#pragma unroll
    for (int r = 0; r < 4; ++r)
      s_act[(16 * w + 4 * g + r) * PITCHH + 16 * t + a] =
          (_Float16)__expf(fmaxf(acc[t][r], 0.f));
  __syncthreads();  // (A) pipeline results + P-clear/segd-init visible
  // read own row's chunk (cross-wave rows), compute exvd in regs
  const half8 e0 = *reinterpret_cast<const half8*>(&s_act[lane * PITCHH + c0]);
  const half8 e1 = *reinterpret_cast<const half8*>(&s_act[lane * PITCHH + c0 + 8]);
  const half8 vd0 = *reinterpret_cast<const half8*>(&s_v[lane * PITCHH + c0]);
  const half8 vd1 = *reinterpret_cast<const half8*>(&s_v[lane * PITCHH + c0 + 8]);
  const half8 m0 = e0 * vd0;  // v_pk_mul_f16; |ex*(v+d)| <= ~13k < f16 max
  const half8 m1 = e1 * vd1;
  __syncthreads();  // (B) all [edge][ch] reads done before transposed overwrite
  // write transposed: ext[ch][edge] over s_act, exvdt[ch][edge] over s_v
#pragma unroll
  for (int j = 0; j < 8; ++j) {
    s_act[(c0 + j) * PITCHH + lane] = e0[j];
    s_act[(c0 + 8 + j) * PITCHH + lane] = e1[j];
    s_v[(c0 + j) * PITCHH + lane] = m0[j];
    s_v[(c0 + 8 + j) * PITCHH + lane] = m1[j];
  }
  if (w == 0) {
    s_p[sid * PITCHH + lane] = (_Float16)1.0f;  // P[sid][edge]=1
    if (head) s_segd[sid] = d;
  }
  if (tid == 0) {
    const bool ts0 = (dm1 != d0);
    const bool te0 = (nseg > 1) || (dp1 != d0);
    headd[blockIdx.x] = ts0 ? -1 : (te0 ? d0 : -2);
    taild[blockIdx.x] = (dp1 != dl) ? -1 : dl;
  }
  __syncthreads();  // (C) transposed data + P + segd ready
  // segment-sum GEMMs: wave w computes seg rows 16w..16w+15 x all 64 ch
  if (16 * w < nseg) {
    const half8 PA0 = *reinterpret_cast<const half8*>(&s_p[(16 * w + a) * PITCHH + 8 * g]);
    const half8 PA1 = *reinterpret_cast<const half8*>(&s_p[(16 * w + a) * PITCHH + 32 + 8 * g]);
    f32x4 accN[4], accD[4];
#pragma unroll
    for (int t = 0; t < 4; ++t) {
      const half8 Bd0 = *reinterpret_cast<const half8*>(&s_act[(16 * t + a) * PITCHH + 8 * g]);
      const half8 Bd1 = *reinterpret_cast<const half8*>(&s_act[(16 * t + a) * PITCHH + 32 + 8 * g]);
      f32x4 cd = {0.f, 0.f, 0.f, 0.f};
      cd = __builtin_amdgcn_mfma_f32_16x16x32_f16(PA0, Bd0, cd, 0, 0, 0);
      cd = __builtin_amdgcn_mfma_f32_16x16x32_f16(PA1, Bd1, cd, 0, 0, 0);
      accD[t] = cd;
      const half8 Bn0 = *reinterpret_cast<const half8*>(&s_v[(16 * t + a) * PITCHH + 8 * g]);
      const half8 Bn1 = *reinterpret_cast<const half8*>(&s_v[(16 * t + a) * PITCHH + 32 + 8 * g]);
      f32x4 cn = {0.f, 0.f, 0.f, 0.f};
      cn = __builtin_amdgcn_mfma_f32_16x16x32_f16(PA0, Bn0, cn, 0, 0, 0);
      cn = __builtin_amdgcn_mfma_f32_16x16x32_f16(PA1, Bn1, cn, 0, 0, 0);
      accN[t] = cn;
    }
    // store: lane owns seg rows {16w+4g+r}, cols {16t+a}
#pragma unroll
    for (int r = 0; r < 4; ++r) {
      const int seg = 16 * w + 4 * g + r;
      const int dseg = s_segd[seg];
      if (dseg >= 0) {
        const bool ts = (seg > 0) || (dm1 != dseg);
        const bool te = (seg < nseg - 1) || (dp1 != dseg);
        if (ts && te) {
          float* np = num + (size_t)dseg * 64 + a;
          float* dp_ = den + (size_t)dseg * 64 + a;
#pragma unroll
          for (int t = 0; t < 4; ++t) {
            np[16 * t] = accN[t][r];
            dp_[16 * t] = accD[t][r];
          }
        } else {
          const int slot = (!ts && te) ? 0 : 1;  // head -> 0; tail/whole -> 1
          float* pb = pbuf + (size_t)blockIdx.x * 256 + slot * 128 + a;
#pragma unroll
          for (int t = 0; t < 4; ++t) {
            pb[16 * t] = accN[t][r];
            pb[64 + 16 * t] = accD[t][r];
          }
        }
      }
    }
  }
}

// ---- finish: resolve boundary partials (unchanged) ----
__global__ __launch_bounds__(128) void finish_kernel(
    const float* __restrict__ pbuf, const int* __restrict__ headd,
    const int* __restrict__ taild, float* __restrict__ num,
    float* __restrict__ den) {
  const int b = blockIdx.x + 1;  // 1..NB-1
  const int t = taild[b - 1];
  if (t < 0) return;
  const int ch = threadIdx.x & 63, arr = threadIdx.x >> 6;
  const int h = headd[b];
  const float tv = pbuf[(size_t)(b - 1) * 256 + 128 + arr * 64 + ch];
  float* dst = (arr ? den : num) + (size_t)t * 64 + ch;
  if (h == t) {
    const float hv = pbuf[(size_t)b * 256 + arr * 64 + ch];
    if (headd[b - 1] != -2) {
      *dst = tv + hv;  // chain exactly {b-1, b}: exclusive owner
    } else {
      atomicAdd(dst, tv + hv);  // chain extends left (degree > 64; ~never)
    }
  } else {
    atomicAdd(dst, tv);  // block b whole-block same-d: chain continues right
  }
}

// ---- Kernel C: out = relu((num/(den+1e-16)) @ W_out + b_out) ----
__global__ __launch_bounds__(256) void out_kernel(
    const float* __restrict__ num, const float* __restrict__ den,
    const float* __restrict__ W_out, const float* __restrict__ b_out,
    float* __restrict__ out) {
  __shared__ __align__(16) float A[64 * PITCH];
  const int tid = threadIdx.x, lane = tid & 63, c0 = wave_c0();
  const int n0 = blockIdx.x * 64;
#pragma unroll
  for (int i = 0; i < 4; ++i) {
    int idx4 = tid + i * 256;
    int e = idx4 >> 4, k4 = (idx4 & 15) * 4;
    int n = n0 + e;
    float4 val = make_float4(0.f, 0.f, 0.f, 0.f);
    if (n < N_NODES) {
      float4 nu = *reinterpret_cast<const float4*>(num + (size_t)n * 64 + k4);
      float4 de = *reinterpret_cast<const float4*>(den + (size_t)n * 64 + k4);
      val.x = nu.x / (de.x + 1e-16f);
      val.y = nu.y / (de.y + 1e-16f);
      val.z = nu.z / (de.z + 1e-16f);
      val.w = nu.w / (de.w + 1e-16f);
    }
    *reinterpret_cast<float4*>(&A[e * PITCH + k4]) = val;
  }
  __syncthreads();
  float o[16];
  wave_gemm16<true, true>(A, lane, c0, W_out, b_out, o);
  const int n = n0 + lane;
  if (n < N_NODES) store4x4(out + (size_t)n * 64 + c0, o);
}

extern "C" void kernel_launch(void* const* d_in, const int* in_sizes, int n_in,
                              void* d_out, int out_size, void* d_ws,
                              size_t ws_size, hipStream_t stream) {
  const float* x     = (const float*)d_in[0];
  const float* pos   = (const float*)d_in[1];
  const int*   ei    = (const int*)d_in[2];
  const float* W_in  = (const float*)d_in[3];
  const float* b_in  = (const float*)d_in[4];
  const float* W_lin = (const float*)d_in[5];
  const float* W_src = (const float*)d_in[6];
  const float* W_dst = (const float*)d_in[7];
  const float* Wp1   = (const float*)d_in[8];
  const float* bp1   = (const float*)d_in[9];
  const float* Wp2   = (const float*)d_in[10];
  const float* bp2   = (const float*)d_in[11];
  const float* Wa1   = (const float*)d_in[12];
  const float* ba1   = (const float*)d_in[13];
  const float* Wa2   = (const float*)d_in[14];
  const float* ba2   = (const float*)d_in[15];
  const float* W_out = (const float*)d_in[16];
  const float* b_out = (const float*)d_in[17];
  float* out = (float*)d_out;

  const size_t NC = (size_t)N_NODES * 64;
  _Float16* adh = (_Float16*)d_ws;               // NC halfs
  _Float16* ash = adh + NC;                      // NC halfs
  _Float16* vh  = ash + NC;                      // NC halfs
  float* num = (float*)(vh + NC);                // NC floats
  float* den = num + NC;                         // NC floats
  int* counts = (int*)(den + NC);                // N_NODES ints
  int* cursor = counts + N_NODES;                // N_NODES ints
  int* pexcl  = cursor + N_NODES;                // N_NODES ints
  int* btot   = pexcl + N_NODES;                 // 128 ints
  int2* order2 = (int2*)(btot + 128);            // N_EDGES int2 (8B aligned)
  float* pbuf  = (float*)(order2 + N_EDGES);     // NB*256 floats (partials)
  int* headd   = (int*)(pbuf + (size_t)NB * 256);// NB ints
  int* taild   = headd + NB;                     // NB ints
  _Float16* wt = (_Float16*)(taild + NB);        // 3*4096 f16 (16B aligned)

  hipMemsetAsync(num, 0, 2 * NC * sizeof(float), stream);    // num+den
  hipMemsetAsync(counts, 0, N_NODES * sizeof(int), stream);  // histogram

  wconv_kernel<<<48, 256, 0, stream>>>(Wp2, Wa1, Wa2, wt);
  hist_kernel<<<(N_EDGES + 255) / 256, 256, 0, stream>>>(ei, counts);
  scan1_kernel<<<N_SCAN_BLOCKS, 1024, 0, stream>>>(counts, pexcl, btot);
  scan2_kernel<<<1, 64, 0, stream>>>(btot);
  scan3_kernel<<<(N_NODES + 255) / 256, 256, 0, stream>>>(pexcl, btot, cursor);
  scatter_kernel<<<(N_EDGES + 255) / 256, 256, 0, stream>>>(ei, cursor, order2);

  node_proj_kernel<<<(N_NODES + 63) / 64, 256, 0, stream>>>(
      x, W_in, b_in, W_lin, W_src, W_dst, adh, ash, vh);
  edge_kernel<<<NB, 256, 0, stream>>>(
      order2, pos, Wp1, bp1, wt, bp2, ba1, ba2, adh, ash, vh, num, den,
      pbuf, headd, taild);
  finish_kernel<<<NB - 1, 128, 0, stream>>>(pbuf, headd, taild, num, den);
  out_kernel<<<(N_NODES + 63) / 64, 256, 0, stream>>>(num, den, W_out, b_out, out);
}

// Round 11
// 763.662 us; speedup vs baseline: 1.0832x; 1.0323x over previous
//
#include <hip/hip_runtime.h>

#define N_NODES 100000
#define N_EDGES 1600000
#define NB (N_EDGES / 64)  // 25000 edge blocks
#define PITCH 68  // fp32 LDS pitch (node/out kernels)
#define PITCHH 72 // f16 LDS pitch: 144B row = 9 quads == 1 mod 8
#define N_SCAN_BLOCKS ((N_NODES + 1023) / 1024)  // 98
#define HIST_BLOCKS (N_EDGES / 256)              // 6250 exact
#define WCONV_BLOCKS 48
#define NPROJ_BLOCKS ((N_NODES + 63) / 64)       // 1563

typedef _Float16 half8 __attribute__((ext_vector_type(8)));
typedef float f32x4 __attribute__((ext_vector_type(4)));

__device__ __forceinline__ int wave_c0() {
  return __builtin_amdgcn_readfirstlane((int)((threadIdx.x >> 6) << 4));
}

// fp32 wave GEMM (node/out paths)
template<bool RELU, bool BIAS>
__device__ __forceinline__ void wave_gemm16(const float* Alds, int lane, int c0,
                                            const float* __restrict__ W,
                                            const float* __restrict__ bias,
                                            float acc[16]) {
#pragma unroll
  for (int j = 0; j < 16; ++j) acc[j] = BIAS ? bias[c0 + j] : 0.0f;
  const float* arow = Alds + lane * PITCH;
#pragma unroll
  for (int k = 0; k < 64; k += 4) {
    const float4 a4 = *reinterpret_cast<const float4*>(arow + k);
    const float av[4] = {a4.x, a4.y, a4.z, a4.w};
#pragma unroll
    for (int kk = 0; kk < 4; ++kk) {
#pragma unroll
      for (int j = 0; j < 16; ++j)
        acc[j] = fmaf(av[kk], W[(k + kk) * 64 + c0 + j], acc[j]);
    }
  }
  if (RELU) {
#pragma unroll
    for (int j = 0; j < 16; ++j) acc[j] = fmaxf(acc[j], 0.0f);
  }
}

__device__ __forceinline__ void store4x4(float* dst, const float a[16]) {
#pragma unroll
  for (int q = 0; q < 4; ++q)
    *reinterpret_cast<float4*>(dst + q * 4) =
        make_float4(a[q * 4], a[q * 4 + 1], a[q * 4 + 2], a[q * 4 + 3]);
}

__device__ __forceinline__ void store16h(_Float16* dst, const float a[16]) {
  half8 h0, h1;
#pragma unroll
  for (int u = 0; u < 8; ++u) {
    h0[u] = (_Float16)a[u];
    h1[u] = (_Float16)a[8 + u];
  }
  *reinterpret_cast<half8*>(dst) = h0;
  *reinterpret_cast<half8*>(dst + 8) = h1;
}

// ---- prep: hist (blocks [0,6250)) + wconv ([6250,6298)) + node_proj (rest) ----
// Fusing overlaps hist's latency-bound atomics with node_proj's VALU GEMMs.
__global__ __launch_bounds__(256) void prep_kernel(
    const int* __restrict__ ei, int* __restrict__ counts,
    const float* __restrict__ Wp2, const float* __restrict__ Wa1,
    const float* __restrict__ Wa2, _Float16* __restrict__ wt,
    const float* __restrict__ x, const float* __restrict__ W_in,
    const float* __restrict__ b_in, const float* __restrict__ W_lin,
    const float* __restrict__ W_src, const float* __restrict__ W_dst,
    _Float16* __restrict__ adh, _Float16* __restrict__ ash,
    _Float16* __restrict__ vh) {
  __shared__ __align__(16) float A[64 * PITCH];
  const int b = blockIdx.x;
  if (b < HIST_BLOCKS) {  // histogram of dst
    const int e = b * 256 + threadIdx.x;
    if (e < N_EDGES) atomicAdd(&counts[ei[N_EDGES + e]], 1);
    return;
  }
  if (b < HIST_BLOCKS + WCONV_BLOCKS) {  // wt[m][j][k] = (f16)W_m[k][j]
    const int t = (b - HIST_BLOCKS) * 256 + threadIdx.x;
    if (t < 3 * 4096) {
      const int m = t >> 12, idx = t & 4095;
      const int j = idx >> 6, k = idx & 63;
      const float* W = (m == 0) ? Wp2 : ((m == 1) ? Wa1 : Wa2);
      wt[m * 4096 + j * 64 + k] = (_Float16)W[k * 64 + j];
    }
    return;
  }
  // node_proj: h = relu(x@W_in+b_in); ad=h@W_dst; as=h@W_src; v=h@W_lin (f16 out)
  const int tid = threadIdx.x, lane = tid & 63, c0 = wave_c0();
  const int n0 = (b - HIST_BLOCKS - WCONV_BLOCKS) * 64;
#pragma unroll
  for (int i = 0; i < 4; ++i) {
    int idx4 = tid + i * 256;
    int e = idx4 >> 4, k4 = (idx4 & 15) * 4;
    int n = n0 + e;
    float4 val = make_float4(0.f, 0.f, 0.f, 0.f);
    if (n < N_NODES) val = *reinterpret_cast<const float4*>(x + (size_t)n * 64 + k4);
    *reinterpret_cast<float4*>(&A[e * PITCH + k4]) = val;
  }
  __syncthreads();
  float h[16];
  wave_gemm16<true, true>(A, lane, c0, W_in, b_in, h);
  __syncthreads();
  store4x4(&A[lane * PITCH + c0], h);
  __syncthreads();
  float o1[16], o2[16], o3[16];
  wave_gemm16<false, false>(A, lane, c0, W_dst, nullptr, o1);
  wave_gemm16<false, false>(A, lane, c0, W_src, nullptr, o2);
  wave_gemm16<false, false>(A, lane, c0, W_lin, nullptr, o3);
  const int n = n0 + lane;
  if (n < N_NODES) {
    store16h(adh + (size_t)n * 64 + c0, o1);
    store16h(ash + (size_t)n * 64 + c0, o2);
    store16h(vh + (size_t)n * 64 + c0, o3);
  }
}

// S1: per-block exclusive scan (1024 elems) + block totals
__global__ __launch_bounds__(1024) void scan1_kernel(const int* __restrict__ counts,
                                                     int* __restrict__ pexcl,
                                                     int* __restrict__ btot) {
  __shared__ int wsum[16];
  const int tid = threadIdx.x, lane = tid & 63, wid = tid >> 6;
  const int idx = blockIdx.x * 1024 + tid;
  const int val = (idx < N_NODES) ? counts[idx] : 0;
  int x = val;
#pragma unroll
  for (int o = 1; o < 64; o <<= 1) {
    int y = __shfl_up(x, o);
    if (lane >= o) x += y;
  }
  if (lane == 63) wsum[wid] = x;
  __syncthreads();
  if (wid == 0) {
    int s = (lane < 16) ? wsum[lane] : 0;
#pragma unroll
    for (int o = 1; o < 16; o <<= 1) {
      int y = __shfl_up(s, o);
      if (lane >= o) s += y;
    }
    if (lane < 16) wsum[lane] = s;
  }
  __syncthreads();
  const int woff = (wid > 0) ? wsum[wid - 1] : 0;
  const int incl = woff + x;
  if (idx < N_NODES) pexcl[idx] = incl - val;
  if (tid == 1023) btot[blockIdx.x] = incl;
}

// S2: single wave exclusive-scans the 98 block totals in place
__global__ __launch_bounds__(64) void scan2_kernel(int* __restrict__ btot) {
  const int lane = threadIdx.x;
  int carry = 0;
  for (int base = 0; base < N_SCAN_BLOCKS; base += 64) {
    const int ii = base + lane;
    const int v = (ii < N_SCAN_BLOCKS) ? btot[ii] : 0;
    int x = v;
#pragma unroll
    for (int o = 1; o < 64; o <<= 1) {
      int y = __shfl_up(x, o);
      if (lane >= o) x += y;
    }
    if (ii < N_SCAN_BLOCKS) btot[ii] = carry + x - v;  // exclusive
    carry += __shfl(x, 63);
  }
}

// scatter with inline cursor: p = atomicAdd(pexcl[d]) + btot[d>>10]
__global__ __launch_bounds__(256) void scatter_kernel(const int* __restrict__ ei,
                                                      int* __restrict__ pexcl,
                                                      const int* __restrict__ btot,
                                                      int2* __restrict__ order2) {
  int e = blockIdx.x * 256 + threadIdx.x;
  if (e < N_EDGES) {
    int s = ei[e];
    int d = ei[N_EDGES + e];
    int p = atomicAdd(&pexcl[d], 1) + btot[d >> 10];
    order2[p] = make_int2(s, d);
  }
}

// MFMA helper: A-frag row = 16w + (lane&15), k = 8*(lane>>4)+e (+32).
// D: row = 16w + 4*(lane>>4)+r, col = 16t + (lane&15).
__device__ __forceinline__ void mfma3(const _Float16* aL, int w, int g, int a,
                                      const _Float16* __restrict__ Wt,
                                      const float* __restrict__ bias,
                                      f32x4 acc[4]) {
  const half8 A0 = *reinterpret_cast<const half8*>(aL + (16 * w + a) * PITCHH + 8 * g);
  const half8 A1 = *reinterpret_cast<const half8*>(aL + (16 * w + a) * PITCHH + 32 + 8 * g);
#pragma unroll
  for (int t = 0; t < 4; ++t) {
    const half8 B0 = *reinterpret_cast<const half8*>(Wt + (16 * t + a) * 64 + 8 * g);
    const half8 B1 = *reinterpret_cast<const half8*>(Wt + (16 * t + a) * 64 + 32 + 8 * g);
    const float bv = bias[16 * t + a];
    f32x4 c = {bv, bv, bv, bv};
    c = __builtin_amdgcn_mfma_f32_16x16x32_f16(A0, B0, c, 0, 0, 0);
    c = __builtin_amdgcn_mfma_f32_16x16x32_f16(A1, B1, c, 0, 0, 0);
    acc[t] = c;
  }
}

// ---- Kernel B: wave-private edge pipeline; epilogue = MFMA segment-sum ----
// (unchanged from R10 -- control for this round's fusion changes)
__global__ __launch_bounds__(256) void edge_kernel(
    const int2* __restrict__ order2, const float* __restrict__ pos,
    const float* __restrict__ Wp1, const float* __restrict__ bp1,
    const _Float16* __restrict__ wt, const float* __restrict__ bp2,
    const float* __restrict__ ba1, const float* __restrict__ ba2,
    const _Float16* __restrict__ adh, const _Float16* __restrict__ ash,
    const _Float16* __restrict__ vh, float* __restrict__ num,
    float* __restrict__ den, float* __restrict__ pbuf,
    int* __restrict__ headd, int* __restrict__ taild) {
  __shared__ __align__(16) _Float16 s_act[64 * PITCHH];
  __shared__ __align__(16) _Float16 s_v[64 * PITCHH];
  __shared__ __align__(16) _Float16 s_p[64 * PITCHH];
  __shared__ int s_segd[64];
  const int tid = threadIdx.x, lane = tid & 63, w = tid >> 6;
  const int g = lane >> 4, a = lane & 15, c0 = w * 16;
  const int i = blockIdx.x * 64 + lane;  // sorted edge slot (E % 64 == 0)
  // clear P + segd (read only after barriers below)
#pragma unroll
  for (int q = tid; q < 576; q += 256)
    *reinterpret_cast<int4*>(&s_p[q * 8]) = make_int4(0, 0, 0, 0);
  if (tid < 64) s_segd[tid] = -1;
  const int2 sd = order2[i];
  const int d = sd.y;  // segment key
  // row-phase mapping: 4 threads per own-wave row (row er, quarter p)
  const int er = 16 * w + (lane >> 2);
  const int p = lane & 3;
  const int2 sd2 = order2[blockIdx.x * 64 + er];
  const int s2 = sd2.x, d2 = sd2.y;
  // prefetch node-row gathers NOW; consumed at a_in phase
  const _Float16* adr = adh + (size_t)d2 * 64 + 16 * p;
  const _Float16* asr = ash + (size_t)s2 * 64 + 16 * p;
  const _Float16* vr  = vh  + (size_t)s2 * 64 + 16 * p;
  const half8 ad0 = *reinterpret_cast<const half8*>(adr);
  const half8 ad1 = *reinterpret_cast<const half8*>(adr + 8);
  const half8 as0 = *reinterpret_cast<const half8*>(asr);
  const half8 as1 = *reinterpret_cast<const half8*>(asr + 8);
  const half8 v0  = *reinterpret_cast<const half8*>(vr);
  const half8 v1  = *reinterpret_cast<const half8*>(vr + 8);
  // boundary probes
  int dm1 = -1, dp1 = -1;
  if (lane == 0 && i > 0) dm1 = order2[i - 1].y;
  if (lane == 63 && i + 1 < N_EDGES) dp1 = order2[i + 1].y;
  dm1 = __shfl(dm1, 0);
  dp1 = __shfl(dp1, 63);
  // segment structure (identical across waves)
  const int dprev = __shfl_up(d, 1);
  const bool head = (lane == 0) || (d != dprev);
  const unsigned long long hb = __ballot(head);
  const unsigned long long maskle =
      (lane == 63) ? ~0ull : ((1ull << (lane + 1)) - 1ull);
  const int sid = __popcll(hb & maskle) - 1;  // this edge's segment id
  const int nseg = __popcll(hb);
  const int d0 = __shfl(d, 0), dl = __shfl(d, 63);
  // stage0: hp(row er, ch 16p..16p+16) = relu(dpos@Wp1+bp1) -- wave-private rows
  {
    const float2 pd = reinterpret_cast<const float2*>(pos)[d2];
    const float2 ps = reinterpret_cast<const float2*>(pos)[s2];
    const float dx = pd.x - ps.x, dy = pd.y - ps.y;
    half8 h0, h1;
#pragma unroll
    for (int u = 0; u < 8; ++u) {
      const int j0 = 16 * p + u, j1 = 16 * p + 8 + u;
      h0[u] = (_Float16)fmaxf(fmaf(dx, Wp1[j0], fmaf(dy, Wp1[64 + j0], bp1[j0])), 0.f);
      h1[u] = (_Float16)fmaxf(fmaf(dx, Wp1[j1], fmaf(dy, Wp1[64 + j1], bp1[j1])), 0.f);
    }
    *reinterpret_cast<half8*>(&s_act[er * PITCHH + 16 * p]) = h0;
    *reinterpret_cast<half8*>(&s_act[er * PITCHH + 16 * p + 8]) = h1;
  }
  f32x4 acc[4];
  // GEMM1: delta = relu(hp@Wp2+bp2) -> in place over hp (own 16 rows)
  mfma3(s_act, w, g, a, wt, bp2, acc);
#pragma unroll
  for (int t = 0; t < 4; ++t)
#pragma unroll
    for (int r = 0; r < 4; ++r)
      s_act[(16 * w + 4 * g + r) * PITCHH + 16 * t + a] =
          (_Float16)fmaxf(acc[t][r], 0.f);
  // a_in = ad[d]-as[s]+delta -> s_act (over delta); v+delta -> s_v  (own rows)
  {
    const half8 dl0 = *reinterpret_cast<const half8*>(&s_act[er * PITCHH + 16 * p]);
    const half8 dl1 = *reinterpret_cast<const half8*>(&s_act[er * PITCHH + 16 * p + 8]);
    *reinterpret_cast<half8*>(&s_act[er * PITCHH + 16 * p]) = ad0 - as0 + dl0;
    *reinterpret_cast<half8*>(&s_act[er * PITCHH + 16 * p + 8]) = ad1 - as1 + dl1;
    *reinterpret_cast<half8*>(&s_v[er * PITCHH + 16 * p]) = v0 + dl0;
    *reinterpret_cast<half8*>(&s_v[er * PITCHH + 16 * p + 8]) = v1 + dl1;
  }
  // GEMM2: ha = relu(a_in@Wa1+ba1) -> s_act (own rows)
  mfma3(s_act, w, g, a, wt + 4096, ba1, acc);
#pragma unroll
  for (int t = 0; t < 4; ++t)
#pragma unroll
    for (int r = 0; r < 4; ++r)
      s_act[(16 * w + 4 * g + r) * PITCHH + 16 * t + a] =
          (_Float16)fmaxf(acc[t][r], 0.f);
  // GEMM3: aat = relu(ha@Wa2+ba2); ex = exp(aat) -> s_act (own rows, over ha)
  mfma3(s_act, w, g, a, wt + 2 * 4096, ba2, acc);
#pragma unroll
  for (int t = 0; t < 4; ++t)
#pragma unroll
    for (int r = 0; r < 4; ++r)
      s_act[(16 * w + 4 * g + r) * PITCHH + 16 * t + a] =
          (_Float16)__expf(fmaxf(acc[t][r], 0.f));
  __syncthreads();  // (A) pipeline results + P-clear/segd-init visible
  // read own row's chunk (cross-wave rows), compute exvd in regs
  const half8 e0 = *reinterpret_cast<const half8*>(&s_act[lane * PITCHH + c0]);
  const half8 e1 = *reinterpret_cast<const half8*>(&s_act[lane * PITCHH + c0 + 8]);
  const half8 vd0 = *reinterpret_cast<const half8*>(&s_v[lane * PITCHH + c0]);
  const half8 vd1 = *reinterpret_cast<const half8*>(&s_v[lane * PITCHH + c0 + 8]);
  const half8 m0 = e0 * vd0;  // v_pk_mul_f16; |ex*(v+d)| <= ~13k < f16 max
  const half8 m1 = e1 * vd1;
  __syncthreads();  // (B) all [edge][ch] reads done before transposed overwrite
  // write transposed: ext[ch][edge] over s_act, exvdt[ch][edge] over s_v
#pragma unroll
  for (int j = 0; j < 8; ++j) {
    s_act[(c0 + j) * PITCHH + lane] = e0[j];
    s_act[(c0 + 8 + j) * PITCHH + lane] = e1[j];
    s_v[(c0 + j) * PITCHH + lane] = m0[j];
    s_v[(c0 + 8 + j) * PITCHH + lane] = m1[j];
  }
  if (w == 0) {
    s_p[sid * PITCHH + lane] = (_Float16)1.0f;  // P[sid][edge]=1
    if (head) s_segd[sid] = d;
  }
  if (tid == 0) {
    const bool ts0 = (dm1 != d0);
    const bool te0 = (nseg > 1) || (dp1 != d0);
    headd[blockIdx.x] = ts0 ? -1 : (te0 ? d0 : -2);
    taild[blockIdx.x] = (dp1 != dl) ? -1 : dl;
  }
  __syncthreads();  // (C) transposed data + P + segd ready
  // segment-sum GEMMs: wave w computes seg rows 16w..16w+15 x all 64 ch
  if (16 * w < nseg) {
    const half8 PA0 = *reinterpret_cast<const half8*>(&s_p[(16 * w + a) * PITCHH + 8 * g]);
    const half8 PA1 = *reinterpret_cast<const half8*>(&s_p[(16 * w + a) * PITCHH + 32 + 8 * g]);
    f32x4 accN[4], accD[4];
#pragma unroll
    for (int t = 0; t < 4; ++t) {
      const half8 Bd0 = *reinterpret_cast<const half8*>(&s_act[(16 * t + a) * PITCHH + 8 * g]);
      const half8 Bd1 = *reinterpret_cast<const half8*>(&s_act[(16 * t + a) * PITCHH + 32 + 8 * g]);
      f32x4 cd = {0.f, 0.f, 0.f, 0.f};
      cd = __builtin_amdgcn_mfma_f32_16x16x32_f16(PA0, Bd0, cd, 0, 0, 0);
      cd = __builtin_amdgcn_mfma_f32_16x16x32_f16(PA1, Bd1, cd, 0, 0, 0);
      accD[t] = cd;
      const half8 Bn0 = *reinterpret_cast<const half8*>(&s_v[(16 * t + a) * PITCHH + 8 * g]);
      const half8 Bn1 = *reinterpret_cast<const half8*>(&s_v[(16 * t + a) * PITCHH + 32 + 8 * g]);
      f32x4 cn = {0.f, 0.f, 0.f, 0.f};
      cn = __builtin_amdgcn_mfma_f32_16x16x32_f16(PA0, Bn0, cn, 0, 0, 0);
      cn = __builtin_amdgcn_mfma_f32_16x16x32_f16(PA1, Bn1, cn, 0, 0, 0);
      accN[t] = cn;
    }
    // store: lane owns seg rows {16w+4g+r}, cols {16t+a}
#pragma unroll
    for (int r = 0; r < 4; ++r) {
      const int seg = 16 * w + 4 * g + r;
      const int dseg = s_segd[seg];
      if (dseg >= 0) {
        const bool ts = (seg > 0) || (dm1 != dseg);
        const bool te = (seg < nseg - 1) || (dp1 != dseg);
        if (ts && te) {
          float* np = num + (size_t)dseg * 64 + a;
          float* dp_ = den + (size_t)dseg * 64 + a;
#pragma unroll
          for (int t = 0; t < 4; ++t) {
            np[16 * t] = accN[t][r];
            dp_[16 * t] = accD[t][r];
          }
        } else {
          const int slot = (!ts && te) ? 0 : 1;  // head -> 0; tail/whole -> 1
          float* pb = pbuf + (size_t)blockIdx.x * 256 + slot * 128 + a;
#pragma unroll
          for (int t = 0; t < 4; ++t) {
            pb[16 * t] = accN[t][r];
            pb[64 + 16 * t] = accD[t][r];
          }
        }
      }
    }
  }
}

// ---- finish: resolve boundary partials (unchanged) ----
__global__ __launch_bounds__(128) void finish_kernel(
    const float* __restrict__ pbuf, const int* __restrict__ headd,
    const int* __restrict__ taild, float* __restrict__ num,
    float* __restrict__ den) {
  const int b = blockIdx.x + 1;  // 1..NB-1
  const int t = taild[b - 1];
  if (t < 0) return;
  const int ch = threadIdx.x & 63, arr = threadIdx.x >> 6;
  const int h = headd[b];
  const float tv = pbuf[(size_t)(b - 1) * 256 + 128 + arr * 64 + ch];
  float* dst = (arr ? den : num) + (size_t)t * 64 + ch;
  if (h == t) {
    const float hv = pbuf[(size_t)b * 256 + arr * 64 + ch];
    if (headd[b - 1] != -2) {
      *dst = tv + hv;  // chain exactly {b-1, b}: exclusive owner
    } else {
      atomicAdd(dst, tv + hv);  // chain extends left (degree > 64; ~never)
    }
  } else {
    atomicAdd(dst, tv);  // block b whole-block same-d: chain continues right
  }
}

// ---- Kernel C: out = relu((num/(den+1e-16)) @ W_out + b_out) ----
__global__ __launch_bounds__(256) void out_kernel(
    const float* __restrict__ num, const float* __restrict__ den,
    const float* __restrict__ W_out, const float* __restrict__ b_out,
    float* __restrict__ out) {
  __shared__ __align__(16) float A[64 * PITCH];
  const int tid = threadIdx.x, lane = tid & 63, c0 = wave_c0();
  const int n0 = blockIdx.x * 64;
#pragma unroll
  for (int i = 0; i < 4; ++i) {
    int idx4 = tid + i * 256;
    int e = idx4 >> 4, k4 = (idx4 & 15) * 4;
    int n = n0 + e;
    float4 val = make_float4(0.f, 0.f, 0.f, 0.f);
    if (n < N_NODES) {
      float4 nu = *reinterpret_cast<const float4*>(num + (size_t)n * 64 + k4);
      float4 de = *reinterpret_cast<const float4*>(den + (size_t)n * 64 + k4);
      val.x = nu.x / (de.x + 1e-16f);
      val.y = nu.y / (de.y + 1e-16f);
      val.z = nu.z / (de.z + 1e-16f);
      val.w = nu.w / (de.w + 1e-16f);
    }
    *reinterpret_cast<float4*>(&A[e * PITCH + k4]) = val;
  }
  __syncthreads();
  float o[16];
  wave_gemm16<true, true>(A, lane, c0, W_out, b_out, o);
  const int n = n0 + lane;
  if (n < N_NODES) store4x4(out + (size_t)n * 64 + c0, o);
}

extern "C" void kernel_launch(void* const* d_in, const int* in_sizes, int n_in,
                              void* d_out, int out_size, void* d_ws,
                              size_t ws_size, hipStream_t stream) {
  const float* x     = (const float*)d_in[0];
  const float* pos   = (const float*)d_in[1];
  const int*   ei    = (const int*)d_in[2];
  const float* W_in  = (const float*)d_in[3];
  const float* b_in  = (const float*)d_in[4];
  const float* W_lin = (const float*)d_in[5];
  const float* W_src = (const float*)d_in[6];
  const float* W_dst = (const float*)d_in[7];
  const float* Wp1   = (const float*)d_in[8];
  const float* bp1   = (const float*)d_in[9];
  const float* Wp2   = (const float*)d_in[10];
  const float* bp2   = (const float*)d_in[11];
  const float* Wa1   = (const float*)d_in[12];
  const float* ba1   = (const float*)d_in[13];
  const float* Wa2   = (const float*)d_in[14];
  const float* ba2   = (const float*)d_in[15];
  const float* W_out = (const float*)d_in[16];
  const float* b_out = (const float*)d_in[17];
  float* out = (float*)d_out;

  const size_t NC = (size_t)N_NODES * 64;
  _Float16* adh = (_Float16*)d_ws;               // NC halfs
  _Float16* ash = adh + NC;                      // NC halfs
  _Float16* vh  = ash + NC;                      // NC halfs
  float* num = (float*)(vh + NC);                // NC floats
  float* den = num + NC;                         // NC floats
  int* counts = (int*)(den + NC);                // N_NODES ints (contig after den)
  int* pexcl  = counts + N_NODES;                // N_NODES ints (live cursor)
  int* btot   = pexcl + N_NODES;                 // 128 ints
  int2* order2 = (int2*)(btot + 128);            // N_EDGES int2 (8B aligned)
  float* pbuf  = (float*)(order2 + N_EDGES);     // NB*256 floats (partials)
  int* headd   = (int*)(pbuf + (size_t)NB * 256);// NB ints
  int* taild   = headd + NB;                     // NB ints
  _Float16* wt = (_Float16*)(taild + NB);        // 3*4096 f16 (16B aligned)

  // single memset: num + den + counts are contiguous
  hipMemsetAsync(num, 0, (2 * NC + N_NODES) * sizeof(float), stream);

  prep_kernel<<<HIST_BLOCKS + WCONV_BLOCKS + NPROJ_BLOCKS, 256, 0, stream>>>(
      ei, counts, Wp2, Wa1, Wa2, wt, x, W_in, b_in, W_lin, W_src, W_dst,
      adh, ash, vh);
  scan1_kernel<<<N_SCAN_BLOCKS, 1024, 0, stream>>>(counts, pexcl, btot);
  scan2_kernel<<<1, 64, 0, stream>>>(btot);
  scatter_kernel<<<(N_EDGES + 255) / 256, 256, 0, stream>>>(ei, pexcl, btot, order2);

  edge_kernel<<<NB, 256, 0, stream>>>(
      order2, pos, Wp1, bp1, wt, bp2, ba1, ba2, adh, ash, vh, num, den,
      pbuf, headd, taild);
  finish_kernel<<<NB - 1, 128, 0, stream>>>(pbuf, headd, taild, num, den);
  out_kernel<<<(N_NODES + 63) / 64, 256, 0, stream>>>(num, den, W_out, b_out, out);
}

// Round 12
// 676.029 us; speedup vs baseline: 1.2236x; 1.1296x over previous
//
#include <hip/hip_runtime.h>

#define N_NODES 100000
#define N_EDGES 1600000
#define NB (N_EDGES / 64)  // 25000 edge blocks
#define PITCH 68  // fp32 LDS pitch (node/out kernels)
#define PITCHH 72 // f16 LDS pitch: 144B row = 9 quads == 1 mod 8
#define N_SCAN_BLOCKS ((N_NODES + 1023) / 1024)  // 98
#define HIST_BLOCKS (N_EDGES / 256)              // 6250 exact
#define WCONV_BLOCKS 48
#define NPROJ_BLOCKS ((N_NODES + 63) / 64)       // 1563

typedef _Float16 half8 __attribute__((ext_vector_type(8)));
typedef float f32x4 __attribute__((ext_vector_type(4)));

__device__ __forceinline__ int wave_c0() {
  return __builtin_amdgcn_readfirstlane((int)((threadIdx.x >> 6) << 4));
}

// fp32 wave GEMM (node/out paths)
template<bool RELU, bool BIAS>
__device__ __forceinline__ void wave_gemm16(const float* Alds, int lane, int c0,
                                            const float* __restrict__ W,
                                            const float* __restrict__ bias,
                                            float acc[16]) {
#pragma unroll
  for (int j = 0; j < 16; ++j) acc[j] = BIAS ? bias[c0 + j] : 0.0f;
  const float* arow = Alds + lane * PITCH;
#pragma unroll
  for (int k = 0; k < 64; k += 4) {
    const float4 a4 = *reinterpret_cast<const float4*>(arow + k);
    const float av[4] = {a4.x, a4.y, a4.z, a4.w};
#pragma unroll
    for (int kk = 0; kk < 4; ++kk) {
#pragma unroll
      for (int j = 0; j < 16; ++j)
        acc[j] = fmaf(av[kk], W[(k + kk) * 64 + c0 + j], acc[j]);
    }
  }
  if (RELU) {
#pragma unroll
    for (int j = 0; j < 16; ++j) acc[j] = fmaxf(acc[j], 0.0f);
  }
}

__device__ __forceinline__ void store4x4(float* dst, const float a[16]) {
#pragma unroll
  for (int q = 0; q < 4; ++q)
    *reinterpret_cast<float4*>(dst + q * 4) =
        make_float4(a[q * 4], a[q * 4 + 1], a[q * 4 + 2], a[q * 4 + 3]);
}

__device__ __forceinline__ void store16h(_Float16* dst, const float a[16]) {
  half8 h0, h1;
#pragma unroll
  for (int u = 0; u < 8; ++u) {
    h0[u] = (_Float16)a[u];
    h1[u] = (_Float16)a[8 + u];
  }
  *reinterpret_cast<half8*>(dst) = h0;
  *reinterpret_cast<half8*>(dst + 8) = h1;
}

// ---- hist (blocks [0,6250)) + wconv ([6250,6298)) ----
__global__ __launch_bounds__(256) void histwconv_kernel(
    const int* __restrict__ ei, int* __restrict__ counts,
    const float* __restrict__ Wp2, const float* __restrict__ Wa1,
    const float* __restrict__ Wa2, _Float16* __restrict__ wt) {
  const int b = blockIdx.x;
  if (b < HIST_BLOCKS) {
    const int e = b * 256 + threadIdx.x;
    if (e < N_EDGES) atomicAdd(&counts[ei[N_EDGES + e]], 1);
    return;
  }
  const int t = (b - HIST_BLOCKS) * 256 + threadIdx.x;
  if (t < 3 * 4096) {
    const int m = t >> 12, idx = t & 4095;
    const int j = idx >> 6, k = idx & 63;
    const float* W = (m == 0) ? Wp2 : ((m == 1) ? Wa1 : Wa2);
    wt[m * 4096 + j * 64 + k] = (_Float16)W[k * 64 + j];
  }
}

// S1: per-block exclusive scan (1024 elems) + block totals
__global__ __launch_bounds__(1024) void scan1_kernel(const int* __restrict__ counts,
                                                     int* __restrict__ pexcl,
                                                     int* __restrict__ btot) {
  __shared__ int wsum[16];
  const int tid = threadIdx.x, lane = tid & 63, wid = tid >> 6;
  const int idx = blockIdx.x * 1024 + tid;
  const int val = (idx < N_NODES) ? counts[idx] : 0;
  int x = val;
#pragma unroll
  for (int o = 1; o < 64; o <<= 1) {
    int y = __shfl_up(x, o);
    if (lane >= o) x += y;
  }
  if (lane == 63) wsum[wid] = x;
  __syncthreads();
  if (wid == 0) {
    int s = (lane < 16) ? wsum[lane] : 0;
#pragma unroll
    for (int o = 1; o < 16; o <<= 1) {
      int y = __shfl_up(s, o);
      if (lane >= o) s += y;
    }
    if (lane < 16) wsum[lane] = s;
  }
  __syncthreads();
  const int woff = (wid > 0) ? wsum[wid - 1] : 0;
  const int incl = woff + x;
  if (idx < N_NODES) pexcl[idx] = incl - val;
  if (tid == 1023) btot[blockIdx.x] = incl;
}

// S2: single wave exclusive-scans the 98 block totals in place
__global__ __launch_bounds__(64) void scan2_kernel(int* __restrict__ btot) {
  const int lane = threadIdx.x;
  int carry = 0;
  for (int base = 0; base < N_SCAN_BLOCKS; base += 64) {
    const int ii = base + lane;
    const int v = (ii < N_SCAN_BLOCKS) ? btot[ii] : 0;
    int x = v;
#pragma unroll
    for (int o = 1; o < 64; o <<= 1) {
      int y = __shfl_up(x, o);
      if (lane >= o) x += y;
    }
    if (ii < N_SCAN_BLOCKS) btot[ii] = carry + x - v;  // exclusive
    carry += __shfl(x, 63);
  }
}

// ---- scatter (4/5 of blocks) interleaved with node_proj (1/5) for overlap ----
__global__ __launch_bounds__(256) void scatnproj_kernel(
    const int* __restrict__ ei, int* __restrict__ pexcl,
    const int* __restrict__ btot, int2* __restrict__ order2,
    const float* __restrict__ x, const float* __restrict__ W_in,
    const float* __restrict__ b_in, const float* __restrict__ W_lin,
    const float* __restrict__ W_src, const float* __restrict__ W_dst,
    _Float16* __restrict__ adh, _Float16* __restrict__ ash,
    _Float16* __restrict__ vh) {
  __shared__ __align__(16) float A[64 * PITCH];
  const int b = blockIdx.x, grp = b / 5, pos = b % 5;
  if (pos < 4) {  // scatter: random cursor atomics + int2 stores (latency-bound)
    const int e = (4 * grp + pos) * 256 + threadIdx.x;
    if (e < N_EDGES) {
      const int s = ei[e];
      const int d = ei[N_EDGES + e];
      const int p = atomicAdd(&pexcl[d], 1) + btot[d >> 10];
      order2[p] = make_int2(s, d);
    }
    return;
  }
  // node_proj (VALU-bound): h = relu(x@W_in+b_in); ad/as/v projections (f16 out)
  const int tid = threadIdx.x, lane = tid & 63, c0 = wave_c0();
  const int n0 = grp * 64;
#pragma unroll
  for (int i = 0; i < 4; ++i) {
    int idx4 = tid + i * 256;
    int e = idx4 >> 4, k4 = (idx4 & 15) * 4;
    int n = n0 + e;
    float4 val = make_float4(0.f, 0.f, 0.f, 0.f);
    if (n < N_NODES) val = *reinterpret_cast<const float4*>(x + (size_t)n * 64 + k4);
    *reinterpret_cast<float4*>(&A[e * PITCH + k4]) = val;
  }
  __syncthreads();
  float h[16];
  wave_gemm16<true, true>(A, lane, c0, W_in, b_in, h);
  __syncthreads();
  store4x4(&A[lane * PITCH + c0], h);
  __syncthreads();
  float o1[16], o2[16], o3[16];
  wave_gemm16<false, false>(A, lane, c0, W_dst, nullptr, o1);
  wave_gemm16<false, false>(A, lane, c0, W_src, nullptr, o2);
  wave_gemm16<false, false>(A, lane, c0, W_lin, nullptr, o3);
  const int n = n0 + lane;
  if (n < N_NODES) {
    store16h(adh + (size_t)n * 64 + c0, o1);
    store16h(ash + (size_t)n * 64 + c0, o2);
    store16h(vh + (size_t)n * 64 + c0, o3);
  }
}

// MFMA helper: A-frag row = 16w + (lane&15), k = 8*(lane>>4)+e (+32).
// D: row = 16w + 4*(lane>>4)+r, col = 16t + (lane&15).
__device__ __forceinline__ void mfma3(const _Float16* aL, int w, int g, int a,
                                      const _Float16* __restrict__ Wt,
                                      const float* __restrict__ bias,
                                      f32x4 acc[4]) {
  const half8 A0 = *reinterpret_cast<const half8*>(aL + (16 * w + a) * PITCHH + 8 * g);
  const half8 A1 = *reinterpret_cast<const half8*>(aL + (16 * w + a) * PITCHH + 32 + 8 * g);
#pragma unroll
  for (int t = 0; t < 4; ++t) {
    const half8 B0 = *reinterpret_cast<const half8*>(Wt + (16 * t + a) * 64 + 8 * g);
    const half8 B1 = *reinterpret_cast<const half8*>(Wt + (16 * t + a) * 64 + 32 + 8 * g);
    const float bv = bias[16 * t + a];
    f32x4 c = {bv, bv, bv, bv};
    c = __builtin_amdgcn_mfma_f32_16x16x32_f16(A0, B0, c, 0, 0, 0);
    c = __builtin_amdgcn_mfma_f32_16x16x32_f16(A1, B1, c, 0, 0, 0);
    acc[t] = c;
  }
}

// ---- Kernel B: wave-private edge pipeline; MFMA segment-sum; complete
// segments divide in-kernel and store fp16 r = num/(den+1e-16) to rh.
// Boundary partials -> pbuf; freak (>2-block) chains -> atomics + flag.
__global__ __launch_bounds__(256) void edge_kernel(
    const int2* __restrict__ order2, const float* __restrict__ pos,
    const float* __restrict__ Wp1, const float* __restrict__ bp1,
    const _Float16* __restrict__ wt, const float* __restrict__ bp2,
    const float* __restrict__ ba1, const float* __restrict__ ba2,
    const _Float16* __restrict__ adh, const _Float16* __restrict__ ash,
    const _Float16* __restrict__ vh, _Float16* __restrict__ rh,
    float* __restrict__ pbuf, int* __restrict__ headd,
    int* __restrict__ taild) {
  __shared__ __align__(16) _Float16 s_act[64 * PITCHH];
  __shared__ __align__(16) _Float16 s_v[64 * PITCHH];
  __shared__ __align__(16) _Float16 s_p[64 * PITCHH];
  __shared__ int s_segd[64];
  const int tid = threadIdx.x, lane = tid & 63, w = tid >> 6;
  const int g = lane >> 4, a = lane & 15, c0 = w * 16;
  const int i = blockIdx.x * 64 + lane;  // sorted edge slot (E % 64 == 0)
  // clear P + segd (read only after barriers below)
#pragma unroll
  for (int q = tid; q < 576; q += 256)
    *reinterpret_cast<int4*>(&s_p[q * 8]) = make_int4(0, 0, 0, 0);
  if (tid < 64) s_segd[tid] = -1;
  const int2 sd = order2[i];
  const int d = sd.y;  // segment key
  // row-phase mapping: 4 threads per own-wave row (row er, quarter p)
  const int er = 16 * w + (lane >> 2);
  const int p = lane & 3;
  const int2 sd2 = order2[blockIdx.x * 64 + er];
  const int s2 = sd2.x, d2 = sd2.y;
  // prefetch node-row gathers NOW; consumed at a_in phase
  const _Float16* adr = adh + (size_t)d2 * 64 + 16 * p;
  const _Float16* asr = ash + (size_t)s2 * 64 + 16 * p;
  const _Float16* vr  = vh  + (size_t)s2 * 64 + 16 * p;
  const half8 ad0 = *reinterpret_cast<const half8*>(adr);
  const half8 ad1 = *reinterpret_cast<const half8*>(adr + 8);
  const half8 as0 = *reinterpret_cast<const half8*>(asr);
  const half8 as1 = *reinterpret_cast<const half8*>(asr + 8);
  const half8 v0  = *reinterpret_cast<const half8*>(vr);
  const half8 v1  = *reinterpret_cast<const half8*>(vr + 8);
  // boundary probes
  int dm1 = -1, dp1 = -1;
  if (lane == 0 && i > 0) dm1 = order2[i - 1].y;
  if (lane == 63 && i + 1 < N_EDGES) dp1 = order2[i + 1].y;
  dm1 = __shfl(dm1, 0);
  dp1 = __shfl(dp1, 63);
  // segment structure (identical across waves)
  const int dprev = __shfl_up(d, 1);
  const bool head = (lane == 0) || (d != dprev);
  const unsigned long long hb = __ballot(head);
  const unsigned long long maskle =
      (lane == 63) ? ~0ull : ((1ull << (lane + 1)) - 1ull);
  const int sid = __popcll(hb & maskle) - 1;  // this edge's segment id
  const int nseg = __popcll(hb);
  const int d0 = __shfl(d, 0), dl = __shfl(d, 63);
  // stage0: hp(row er, ch 16p..16p+16) = relu(dpos@Wp1+bp1) -- wave-private rows
  {
    const float2 pd = reinterpret_cast<const float2*>(pos)[d2];
    const float2 ps = reinterpret_cast<const float2*>(pos)[s2];
    const float dx = pd.x - ps.x, dy = pd.y - ps.y;
    half8 h0, h1;
#pragma unroll
    for (int u = 0; u < 8; ++u) {
      const int j0 = 16 * p + u, j1 = 16 * p + 8 + u;
      h0[u] = (_Float16)fmaxf(fmaf(dx, Wp1[j0], fmaf(dy, Wp1[64 + j0], bp1[j0])), 0.f);
      h1[u] = (_Float16)fmaxf(fmaf(dx, Wp1[j1], fmaf(dy, Wp1[64 + j1], bp1[j1])), 0.f);
    }
    *reinterpret_cast<half8*>(&s_act[er * PITCHH + 16 * p]) = h0;
    *reinterpret_cast<half8*>(&s_act[er * PITCHH + 16 * p + 8]) = h1;
  }
  f32x4 acc[4];
  // GEMM1: delta = relu(hp@Wp2+bp2) -> in place over hp (own 16 rows)
  mfma3(s_act, w, g, a, wt, bp2, acc);
#pragma unroll
  for (int t = 0; t < 4; ++t)
#pragma unroll
    for (int r = 0; r < 4; ++r)
      s_act[(16 * w + 4 * g + r) * PITCHH + 16 * t + a] =
          (_Float16)fmaxf(acc[t][r], 0.f);
  // a_in = ad[d]-as[s]+delta -> s_act (over delta); v+delta -> s_v  (own rows)
  {
    const half8 dl0 = *reinterpret_cast<const half8*>(&s_act[er * PITCHH + 16 * p]);
    const half8 dl1 = *reinterpret_cast<const half8*>(&s_act[er * PITCHH + 16 * p + 8]);
    *reinterpret_cast<half8*>(&s_act[er * PITCHH + 16 * p]) = ad0 - as0 + dl0;
    *reinterpret_cast<half8*>(&s_act[er * PITCHH + 16 * p + 8]) = ad1 - as1 + dl1;
    *reinterpret_cast<half8*>(&s_v[er * PITCHH + 16 * p]) = v0 + dl0;
    *reinterpret_cast<half8*>(&s_v[er * PITCHH + 16 * p + 8]) = v1 + dl1;
  }
  // GEMM2: ha = relu(a_in@Wa1+ba1) -> s_act (own rows)
  mfma3(s_act, w, g, a, wt + 4096, ba1, acc);
#pragma unroll
  for (int t = 0; t < 4; ++t)
#pragma unroll
    for (int r = 0; r < 4; ++r)
      s_act[(16 * w + 4 * g + r) * PITCHH + 16 * t + a] =
          (_Float16)fmaxf(acc[t][r], 0.f);
  // GEMM3: aat = relu(ha@Wa2+ba2); ex = exp(aat) -> s_act (own rows, over ha)
  mfma3(s_act, w, g, a, wt + 2 * 4096, ba2, acc);
#pragma unroll
  for (int t = 0; t < 4; ++t)
#pragma unroll
    for (int r = 0; r < 4; ++r)
      s_act[(16 * w + 4 * g + r) * PITCHH + 16 * t + a] =
          (_Float16)__expf(fmaxf(acc[t][r], 0.f));
  __syncthreads();  // (A) pipeline results + P-clear/segd-init visible
  // read own row's chunk (cross-wave rows), compute exvd in regs
  const half8 e0 = *reinterpret_cast<const half8*>(&s_act[lane * PITCHH + c0]);
  const half8 e1 = *reinterpret_cast<const half8*>(&s_act[lane * PITCHH + c0 + 8]);
  const half8 vd0 = *reinterpret_cast<const half8*>(&s_v[lane * PITCHH + c0]);
  const half8 vd1 = *reinterpret_cast<const half8*>(&s_v[lane * PITCHH + c0 + 8]);
  const half8 m0 = e0 * vd0;  // v_pk_mul_f16; |ex*(v+d)| <= ~13k < f16 max
  const half8 m1 = e1 * vd1;
  __syncthreads();  // (B) all [edge][ch] reads done before transposed overwrite
  // write transposed: ext[ch][edge] over s_act, exvdt[ch][edge] over s_v
#pragma unroll
  for (int j = 0; j < 8; ++j) {
    s_act[(c0 + j) * PITCHH + lane] = e0[j];
    s_act[(c0 + 8 + j) * PITCHH + lane] = e1[j];
    s_v[(c0 + j) * PITCHH + lane] = m0[j];
    s_v[(c0 + 8 + j) * PITCHH + lane] = m1[j];
  }
  if (w == 0) {
    s_p[sid * PITCHH + lane] = (_Float16)1.0f;  // P[sid][edge]=1
    if (head) s_segd[sid] = d;
  }
  if (tid == 0) {
    const bool ts0 = (dm1 != d0);
    const bool te0 = (nseg > 1) || (dp1 != d0);
    headd[blockIdx.x] = ts0 ? -1 : (te0 ? d0 : -2);
    taild[blockIdx.x] = (dp1 != dl) ? -1 : dl;
  }
  __syncthreads();  // (C) transposed data + P + segd ready
  // segment-sum GEMMs: wave w computes seg rows 16w..16w+15 x all 64 ch
  if (16 * w < nseg) {
    const half8 PA0 = *reinterpret_cast<const half8*>(&s_p[(16 * w + a) * PITCHH + 8 * g]);
    const half8 PA1 = *reinterpret_cast<const half8*>(&s_p[(16 * w + a) * PITCHH + 32 + 8 * g]);
    f32x4 accN[4], accD[4];
#pragma unroll
    for (int t = 0; t < 4; ++t) {
      const half8 Bd0 = *reinterpret_cast<const half8*>(&s_act[(16 * t + a) * PITCHH + 8 * g]);
      const half8 Bd1 = *reinterpret_cast<const half8*>(&s_act[(16 * t + a) * PITCHH + 32 + 8 * g]);
      f32x4 cd = {0.f, 0.f, 0.f, 0.f};
      cd = __builtin_amdgcn_mfma_f32_16x16x32_f16(PA0, Bd0, cd, 0, 0, 0);
      cd = __builtin_amdgcn_mfma_f32_16x16x32_f16(PA1, Bd1, cd, 0, 0, 0);
      accD[t] = cd;
      const half8 Bn0 = *reinterpret_cast<const half8*>(&s_v[(16 * t + a) * PITCHH + 8 * g]);
      const half8 Bn1 = *reinterpret_cast<const half8*>(&s_v[(16 * t + a) * PITCHH + 32 + 8 * g]);
      f32x4 cn = {0.f, 0.f, 0.f, 0.f};
      cn = __builtin_amdgcn_mfma_f32_16x16x32_f16(PA0, Bn0, cn, 0, 0, 0);
      cn = __builtin_amdgcn_mfma_f32_16x16x32_f16(PA1, Bn1, cn, 0, 0, 0);
      accN[t] = cn;
    }
    // store: lane owns seg rows {16w+4g+r}, cols {16t+a}
#pragma unroll
    for (int r = 0; r < 4; ++r) {
      const int seg = 16 * w + 4 * g + r;
      const int dseg = s_segd[seg];
      if (dseg >= 0) {
        const bool ts = (seg > 0) || (dm1 != dseg);
        const bool te = (seg < nseg - 1) || (dp1 != dseg);
        if (ts && te) {
          // complete segment: final sums -> divide here, store fp16 r
          _Float16* rp = rh + (size_t)dseg * 64 + a;
#pragma unroll
          for (int t = 0; t < 4; ++t)
            rp[16 * t] = (_Float16)(accN[t][r] / (accD[t][r] + 1e-16f));
        } else {
          const int slot = (!ts && te) ? 0 : 1;  // head -> 0; tail/whole -> 1
          float* pb = pbuf + (size_t)blockIdx.x * 256 + slot * 128 + a;
#pragma unroll
          for (int t = 0; t < 4; ++t) {
            pb[16 * t] = accN[t][r];
            pb[64 + 16 * t] = accD[t][r];
          }
        }
      }
    }
  }
}

// ---- finish: merge boundary partials -> fp16 r; freak chains -> atomics+flag
__global__ __launch_bounds__(64) void finish_kernel(
    const float* __restrict__ pbuf, const int* __restrict__ headd,
    const int* __restrict__ taild, float* __restrict__ num,
    float* __restrict__ den, int* __restrict__ flags,
    _Float16* __restrict__ rh) {
  const int b = blockIdx.x + 1;  // 1..NB-1
  const int t = taild[b - 1];
  if (t < 0) return;
  const int ch = threadIdx.x;  // 0..63
  const int h = headd[b];
  const float tvN = pbuf[(size_t)(b - 1) * 256 + 128 + ch];
  const float tvD = pbuf[(size_t)(b - 1) * 256 + 128 + 64 + ch];
  if (h == t && headd[b - 1] != -2) {
    // chain exactly {b-1, b}: exclusive owner -> divide + fp16 store
    const float hvN = pbuf[(size_t)b * 256 + ch];
    const float hvD = pbuf[(size_t)b * 256 + 64 + ch];
    rh[(size_t)t * 64 + ch] = (_Float16)((tvN + hvN) / (tvD + hvD + 1e-16f));
  } else if (h == t) {
    // terminal boundary of a >2-block chain (degree > 64; ~never)
    const float hvN = pbuf[(size_t)b * 256 + ch];
    const float hvD = pbuf[(size_t)b * 256 + 64 + ch];
    atomicAdd(&num[(size_t)t * 64 + ch], tvN + hvN);
    atomicAdd(&den[(size_t)t * 64 + ch], tvD + hvD);
    if (ch == 0) flags[t] = 1;
  } else {
    // h == -2: block b whole-block same-d -> chain continues right
    atomicAdd(&num[(size_t)t * 64 + ch], tvN);
    atomicAdd(&den[(size_t)t * 64 + ch], tvD);
    if (ch == 0) flags[t] = 1;
  }
}

// ---- Kernel C: out = relu(r @ W_out + b_out), r from fp16 rh (or num/den if flagged)
__global__ __launch_bounds__(256) void out_kernel(
    const _Float16* __restrict__ rh, const int* __restrict__ flags,
    const float* __restrict__ num, const float* __restrict__ den,
    const float* __restrict__ W_out, const float* __restrict__ b_out,
    float* __restrict__ out) {
  __shared__ __align__(16) float A[64 * PITCH];
  const int tid = threadIdx.x, lane = tid & 63, c0 = wave_c0();
  const int n0 = blockIdx.x * 64;
  // stage: thread handles node e = tid>>2, 16-ch chunk q = tid&3
  {
    const int e = tid >> 2, q = tid & 3;
    const int n = n0 + e;
    float vv[16];
#pragma unroll
    for (int u = 0; u < 16; ++u) vv[u] = 0.f;
    if (n < N_NODES) {
      if (__builtin_expect(flags[n], 0)) {
#pragma unroll
        for (int u = 0; u < 4; ++u) {
          const float4 nu = *reinterpret_cast<const float4*>(num + (size_t)n * 64 + q * 16 + 4 * u);
          const float4 de = *reinterpret_cast<const float4*>(den + (size_t)n * 64 + q * 16 + 4 * u);
          vv[4 * u + 0] = nu.x / (de.x + 1e-16f);
          vv[4 * u + 1] = nu.y / (de.y + 1e-16f);
          vv[4 * u + 2] = nu.z / (de.z + 1e-16f);
          vv[4 * u + 3] = nu.w / (de.w + 1e-16f);
        }
      } else {
        const half8 r0 = *reinterpret_cast<const half8*>(rh + (size_t)n * 64 + q * 16);
        const half8 r1 = *reinterpret_cast<const half8*>(rh + (size_t)n * 64 + q * 16 + 8);
#pragma unroll
        for (int u = 0; u < 8; ++u) {
          vv[u] = (float)r0[u];
          vv[8 + u] = (float)r1[u];
        }
      }
    }
#pragma unroll
    for (int u = 0; u < 4; ++u)
      *reinterpret_cast<float4*>(&A[e * PITCH + q * 16 + 4 * u]) =
          make_float4(vv[4 * u], vv[4 * u + 1], vv[4 * u + 2], vv[4 * u + 3]);
  }
  __syncthreads();
  float o[16];
  wave_gemm16<true, true>(A, lane, c0, W_out, b_out, o);
  const int n = n0 + lane;
  if (n < N_NODES) store4x4(out + (size_t)n * 64 + c0, o);
}

extern "C" void kernel_launch(void* const* d_in, const int* in_sizes, int n_in,
                              void* d_out, int out_size, void* d_ws,
                              size_t ws_size, hipStream_t stream) {
  const float* x     = (const float*)d_in[0];
  const float* pos   = (const float*)d_in[1];
  const int*   ei    = (const int*)d_in[2];
  const float* W_in  = (const float*)d_in[3];
  const float* b_in  = (const float*)d_in[4];
  const float* W_lin = (const float*)d_in[5];
  const float* W_src = (const float*)d_in[6];
  const float* W_dst = (const float*)d_in[7];
  const float* Wp1   = (const float*)d_in[8];
  const float* bp1   = (const float*)d_in[9];
  const float* Wp2   = (const float*)d_in[10];
  const float* bp2   = (const float*)d_in[11];
  const float* Wa1   = (const float*)d_in[12];
  const float* ba1   = (const float*)d_in[13];
  const float* Wa2   = (const float*)d_in[14];
  const float* ba2   = (const float*)d_in[15];
  const float* W_out = (const float*)d_in[16];
  const float* b_out = (const float*)d_in[17];
  float* out = (float*)d_out;

  const size_t NC = (size_t)N_NODES * 64;
  _Float16* adh = (_Float16*)d_ws;                // NC halfs (no zero)
  _Float16* ash = adh + NC;                       // NC halfs
  _Float16* vh  = ash + NC;                       // NC halfs
  float* num    = (float*)(vh + NC);              // NC f32  [zeroed]
  float* den    = num + NC;                       // NC f32  [zeroed]
  int* counts   = (int*)(den + NC);               // N i32   [zeroed]
  int* flags    = counts + N_NODES;               // N i32   [zeroed]
  _Float16* rh  = (_Float16*)(flags + N_NODES);   // NC f16  [zeroed]
  int* pexcl    = (int*)(rh + NC);                // N i32 (scan1 writes)
  int* btot     = pexcl + N_NODES;                // 128 i32
  int2* order2  = (int2*)(btot + 128);            // E int2 (8B aligned)
  float* pbuf   = (float*)(order2 + N_EDGES);     // NB*256 f32 (partials)
  int* headd    = (int*)(pbuf + (size_t)NB * 256);// NB i32
  int* taild    = headd + NB;                     // NB i32
  _Float16* wt  = (_Float16*)(taild + NB);        // 3*4096 f16 (16B aligned)

  // single memset: num+den+counts+flags+rh are contiguous
  hipMemsetAsync(num, 0,
                 2 * NC * sizeof(float) + 2 * N_NODES * sizeof(int) +
                     NC * sizeof(_Float16),
                 stream);

  histwconv_kernel<<<HIST_BLOCKS + WCONV_BLOCKS, 256, 0, stream>>>(
      ei, counts, Wp2, Wa1, Wa2, wt);
  scan1_kernel<<<N_SCAN_BLOCKS, 1024, 0, stream>>>(counts, pexcl, btot);
  scan2_kernel<<<1, 64, 0, stream>>>(btot);
  scatnproj_kernel<<<5 * NPROJ_BLOCKS, 256, 0, stream>>>(
      ei, pexcl, btot, order2, x, W_in, b_in, W_lin, W_src, W_dst,
      adh, ash, vh);

  edge_kernel<<<NB, 256, 0, stream>>>(
      order2, pos, Wp1, bp1, wt, bp2, ba1, ba2, adh, ash, vh, rh,
      pbuf, headd, taild);
  finish_kernel<<<NB - 1, 64, 0, stream>>>(pbuf, headd, taild, num, den,
                                           flags, rh);
  out_kernel<<<(N_NODES + 63) / 64, 256, 0, stream>>>(rh, flags, num, den,
                                                      W_out, b_out, out);
}